// Round 1
// baseline (6190.085 us; speedup 1.0000x reference)
//
#include <hip/hip_runtime.h>
#include <hip/hip_bf16.h>
#include <float.h>
#include <math.h>

#define NN 30000
#define NE 70000
#define NG 1024
#define NT 5
#define FI 75
#define NL 4

// AVG_DEG_LOG = (100*ln2 + 400*ln3 + 300*ln4 + 50*ln5)/850
#define AMP_DENOM 1.1824939264481302f

// ---------------- CSR build ----------------
__global__ __launch_bounds__(256) void k_deg(const int* __restrict__ dst, int* __restrict__ deg) {
    int e = blockIdx.x * 256 + threadIdx.x;
    if (e < NE) atomicAdd(&deg[dst[e]], 1);
}

__global__ __launch_bounds__(1024) void k_scan(const int* __restrict__ deg, int* __restrict__ rowptr) {
    __shared__ int s[1024];
    __shared__ int carry;
    int tid = threadIdx.x;
    if (tid == 0) carry = 0;
    __syncthreads();
    for (int base = 0; base < NN; base += 1024) {
        int i = base + tid;
        int v = (i < NN) ? deg[i] : 0;
        s[tid] = v;
        __syncthreads();
        for (int off = 1; off < 1024; off <<= 1) {
            int t = (tid >= off) ? s[tid - off] : 0;
            __syncthreads();
            s[tid] += t;
            __syncthreads();
        }
        if (i < NN) rowptr[i] = carry + s[tid] - v;
        int tot = s[1023];
        __syncthreads();
        if (tid == 0) carry += tot;
        __syncthreads();
    }
    if (tid == 0) rowptr[NN] = carry;
}

__global__ __launch_bounds__(256) void k_scatter(const int* __restrict__ src, const int* __restrict__ dst,
                                                 const int* __restrict__ attr, const int* __restrict__ rowptr,
                                                 int* __restrict__ fill, int* __restrict__ csr) {
    int e = blockIdx.x * 256 + threadIdx.x;
    if (e < NE) {
        int d = dst[e];
        int pos = rowptr[d] + atomicAdd(&fill[d], 1);
        csr[pos] = src[e] | (attr[e] << 20);
    }
}

// ---------------- embedding ----------------
__global__ __launch_bounds__(256) void k_h0(const int* __restrict__ x, const float* __restrict__ emb,
                                            float* __restrict__ h) {
    int idx = blockIdx.x * 256 + threadIdx.x;
    if (idx < NN * FI) {
        int n = idx / FI, f = idx % FI;
        h[idx] = emb[x[n] * FI + f];
    }
}

// ---------------- per-layer edge-type table (4 x 375), also zeros BN sums ----------------
__global__ __launch_bounds__(384) void k_tbl(const float* __restrict__ edge_emb, const float* __restrict__ enc_w,
                                             const float* __restrict__ enc_b, const float* __restrict__ pre_w,
                                             const float* __restrict__ pre_b, int l,
                                             float* __restrict__ tbl, float* __restrict__ bnsum) {
    __shared__ float e4[4][FI];
    int tid = threadIdx.x;
    if (tid < 150) bnsum[tid] = 0.0f;
    if (tid < 300) {
        int a = tid / FI, f = tid % FI;
        float acc = enc_b[l * FI + f];
        for (int k = 0; k < 50; k++)
            acc += edge_emb[a * 50 + k] * enc_w[(l * 50 + k) * FI + f];
        e4[a][f] = acc;
    }
    __syncthreads();
    for (int idx = tid; idx < 4 * 375; idx += 384) {
        int a = idx / 375, c = idx % 375;
        int t = c / FI, o = c % FI;
        const float* wp = pre_w + ((size_t)(l * NT + t) * 225 + 150) * FI + o;
        float acc = pre_b[(l * NT + t) * FI + o];
        for (int f = 0; f < FI; f++)
            acc += e4[a][f] * wp[f * FI];
        tbl[idx] = acc;
    }
}

// ---------------- AB = h @ [Wdst | Wsrc]  (M=30000, K=75, N=750) -> bf16 ----------------
__global__ __launch_bounds__(256) void k_preab(const float* __restrict__ h, const float* __restrict__ pre_w,
                                               int l, __hip_bfloat16* __restrict__ AB) {
    __shared__ __align__(16) float sh[32][76];
    __shared__ __align__(16) float sw[75][132];
    int tid = threadIdx.x;
    int bm = blockIdx.x * 32;
    int bn = blockIdx.y * 128;

    for (int idx = tid; idx < 75 * 128; idx += 256) {
        int k = idx >> 7, jj = idx & 127;
        int j = bn + jj;
        float w = 0.0f;
        if (j < 750) {
            int jm = (j < 375) ? j : (j - 375);
            int t = jm / FI, o = jm % FI;
            int row = (j < 375) ? k : (75 + k);
            w = pre_w[((size_t)(l * NT + t) * 225 + row) * FI + o];
        }
        sw[k][jj] = w;
    }
    for (int idx = tid; idx < 32 * 75; idx += 256) {
        int r = idx / 75, f = idx % 75;
        int n = bm + r;
        sh[r][f] = (n < NN) ? h[n * FI + f] : 0.0f;
    }
    __syncthreads();

    int tx = tid & 31, ty = tid >> 5;
    float acc[4][4] = {};
    for (int k = 0; k < 75; k++) {
        float4 bv = *reinterpret_cast<const float4*>(&sw[k][tx * 4]);
        float a0 = sh[ty * 4 + 0][k], a1 = sh[ty * 4 + 1][k];
        float a2 = sh[ty * 4 + 2][k], a3 = sh[ty * 4 + 3][k];
        acc[0][0] += a0 * bv.x; acc[0][1] += a0 * bv.y; acc[0][2] += a0 * bv.z; acc[0][3] += a0 * bv.w;
        acc[1][0] += a1 * bv.x; acc[1][1] += a1 * bv.y; acc[1][2] += a1 * bv.z; acc[1][3] += a1 * bv.w;
        acc[2][0] += a2 * bv.x; acc[2][1] += a2 * bv.y; acc[2][2] += a2 * bv.z; acc[2][3] += a2 * bv.w;
        acc[3][0] += a3 * bv.x; acc[3][1] += a3 * bv.y; acc[3][2] += a3 * bv.z; acc[3][3] += a3 * bv.w;
    }
    for (int i = 0; i < 4; i++) {
        int n = bm + ty * 4 + i;
        if (n >= NN) continue;
        for (int j = 0; j < 4; j++) {
            int col = bn + tx * 4 + j;
            if (col < 750) AB[(size_t)n * 750 + col] = __float2bfloat16(acc[i][j]);
        }
    }
}

// ---------------- fused: aggregate + post-NN + lin + BN partials ----------------
__global__ __launch_bounds__(320) void k_fused(const __hip_bfloat16* __restrict__ AB, const float* __restrict__ h,
                                               const float* __restrict__ tbl, const int* __restrict__ rowptr,
                                               const int* __restrict__ csr, const float* __restrict__ post_w,
                                               const float* __restrict__ post_b, const float* __restrict__ lin_w,
                                               const float* __restrict__ lin_b, int l,
                                               float* __restrict__ z, float* __restrict__ bnsum) {
    __shared__ float s_agg[8][1505];
    __shared__ float s_h[8][76];
    __shared__ float s_y[8][76];
    __shared__ float s_tbl[1500];
    __shared__ float s_amp[8], s_inv[8];
    __shared__ float s_bn[75], s_bn2[75];

    int tid = threadIdx.x;
    int n0 = blockIdx.x * 8;

    for (int idx = tid; idx < 1500; idx += 320) s_tbl[idx] = tbl[idx];
    for (int idx = tid; idx < 600; idx += 320) {
        int i = idx / 75, f = idx % 75;
        s_h[i][f] = h[(n0 + i) * FI + f];
    }
    if (tid < 75) { s_bn[tid] = 0.0f; s_bn2[tid] = 0.0f; }
    if (tid < 8) {
        int n = n0 + tid;
        int dg = rowptr[n + 1] - rowptr[n];
        float cnt = fmaxf((float)dg, 1.0f);
        float ampv = logf(cnt + 1.0f) * (1.0f / AMP_DENOM);
        s_amp[tid] = ampv;
        s_inv[tid] = 1.0f / ampv;
    }
    __syncthreads();

    // phase 1: stats over v = B[src] + tbl[attr]; then shift by A (std shift-invariant)
    {
        int i = tid / 40, fp = tid % 40;
        int n = n0 + i;
        int base = rowptr[n];
        int dg = rowptr[n + 1] - base;
        for (int f = fp; f < 375; f += 40) {
            float sum = 0.0f, ss = 0.0f, mn = FLT_MAX, mx = -FLT_MAX;
            for (int k = 0; k < dg; k++) {
                int pk = csr[base + k];
                int s = pk & 0xFFFFF;
                int a = pk >> 20;
                float v = __bfloat162float(AB[(size_t)s * 750 + 375 + f]) + s_tbl[a * 375 + f];
                sum += v; ss += v * v;
                mn = fminf(mn, v); mx = fmaxf(mx, v);
            }
            int t = f / 75, of = f % 75;
            int c = t * 300 + of;
            if (dg > 0) {
                float Af = __bfloat162float(AB[(size_t)n * 750 + f]);
                float cnt = (float)dg;
                float mv = sum / cnt;
                float var = ss / cnt - mv * mv;
                s_agg[i][c]       = Af + mv;
                s_agg[i][c + 75]  = Af + mn;
                s_agg[i][c + 150] = Af + mx;
                s_agg[i][c + 225] = sqrtf(fmaxf(var, 0.0f) + 1e-5f);
            } else {
                s_agg[i][c] = 0.0f; s_agg[i][c + 75] = 0.0f; s_agg[i][c + 150] = 0.0f;
                s_agg[i][c + 225] = 0.0031622776601683794f;  // sqrt(1e-5)
            }
        }
    }
    __syncthreads();

    // phase 2: post-NN. lanes: node fastest (8-node weight broadcast), tower uniform per wave.
    {
        int ni = tid & 7;
        int cw = tid >> 3;        // [0,40)
        int t = cw >> 3;          // [0,5)
        int oc = cw & 7;          // [0,8)
        float amp = s_amp[ni], inv = s_inv[ni];
        const float* qw = post_w + (size_t)(l * NT + t) * 975 * 15;
        int o0 = oc, o1 = oc + 8;
        bool has1 = (o1 < 15);
        float acc0 = post_b[(l * NT + t) * 15 + o0];
        float acc1 = has1 ? post_b[(l * NT + t) * 15 + o1] : 0.0f;

        const float* wr = qw;
        for (int f = 0; f < 75; f++) {
            float hv = s_h[ni][f];
            acc0 += hv * wr[o0];
            if (has1) acc1 += hv * wr[o1];
            wr += 15;
        }
        const float* r1 = qw + 75 * 15;
        const float* r2 = qw + 375 * 15;
        const float* r3 = qw + 675 * 15;
        const float* ag = &s_agg[ni][t * 300];
        #pragma unroll 4
        for (int j = 0; j < 300; j++) {
            float av = ag[j];
            float a1 = av * amp, a2 = av * inv;
            acc0 += av * r1[o0] + a1 * r2[o0] + a2 * r3[o0];
            if (has1) acc1 += av * r1[o1] + a1 * r2[o1] + a2 * r3[o1];
            r1 += 15; r2 += 15; r3 += 15;
        }
        s_y[ni][t * 15 + o0] = acc0;
        if (has1) s_y[ni][t * 15 + o1] = acc1;
    }
    __syncthreads();

    // lin + BN partials + write pre-BN z
    for (int idx = tid; idx < 600; idx += 320) {
        int ni = idx & 7, c = idx >> 3;
        int n = n0 + ni;
        const float* lwp = lin_w + (size_t)l * 75 * 75;
        float acc = lin_b[l * 75 + c];
        for (int k = 0; k < 75; k++) acc += s_y[ni][k] * lwp[k * 75 + c];
        z[(size_t)n * 75 + c] = acc;
        atomicAdd(&s_bn[c], acc);
        atomicAdd(&s_bn2[c], acc * acc);
    }
    __syncthreads();
    if (tid < 75) {
        atomicAdd(&bnsum[tid], s_bn[tid]);
        atomicAdd(&bnsum[75 + tid], s_bn2[tid]);
    }
}

// ---------------- BN + ReLU ----------------
__global__ __launch_bounds__(256) void k_bn(const float* __restrict__ z, const float* __restrict__ bnsum,
                                            const float* __restrict__ bn_g, const float* __restrict__ bn_b,
                                            int l, float* __restrict__ h) {
    int idx = blockIdx.x * 256 + threadIdx.x;
    if (idx < NN * 75) {
        int c = idx % 75;
        float mu = bnsum[c] * (1.0f / NN);
        float msq = bnsum[75 + c] * (1.0f / NN);
        float var = msq - mu * mu;
        float v = (z[idx] - mu) * rsqrtf(var + 1e-5f) * bn_g[l * 75 + c] + bn_b[l * 75 + c];
        h[idx] = fmaxf(v, 0.0f);
    }
}

// ---------------- pooling + MLP ----------------
__global__ __launch_bounds__(256) void k_pool(const float* __restrict__ h, const int* __restrict__ batch,
                                              float* __restrict__ hg) {
    int idx = blockIdx.x * 256 + threadIdx.x;
    if (idx < NN * 75) {
        int n = idx / 75, f = idx % 75;
        atomicAdd(&hg[batch[n] * 75 + f], h[idx]);
    }
}

__global__ __launch_bounds__(64) void k_mlp(const float* __restrict__ hg,
                                            const float* __restrict__ w1, const float* __restrict__ b1,
                                            const float* __restrict__ w2, const float* __restrict__ b2,
                                            const float* __restrict__ w3, const float* __restrict__ b3,
                                            float* __restrict__ out) {
    __shared__ float zin[75], z1[50], z2[25];
    int g = blockIdx.x, tid = threadIdx.x;
    for (int k = tid; k < 75; k += 64) zin[k] = hg[g * 75 + k];
    __syncthreads();
    if (tid < 50) {
        float acc = b1[tid];
        for (int k = 0; k < 75; k++) acc += zin[k] * w1[k * 50 + tid];
        z1[tid] = fmaxf(acc, 0.0f);
    }
    __syncthreads();
    if (tid < 25) {
        float acc = b2[tid];
        for (int k = 0; k < 50; k++) acc += z1[k] * w2[k * 25 + tid];
        z2[tid] = fmaxf(acc, 0.0f);
    }
    __syncthreads();
    if (tid == 0) {
        float acc = b3[0];
        for (int k = 0; k < 25; k++) acc += z2[k] * w3[k];
        out[g] = acc;
    }
}

extern "C" void kernel_launch(void* const* d_in, const int* in_sizes, int n_in,
                              void* d_out, int out_size, void* d_ws, size_t ws_size,
                              hipStream_t stream) {
    const int* x        = (const int*)d_in[0];
    const int* ei       = (const int*)d_in[1];
    const int* eattr    = (const int*)d_in[2];
    const int* batch    = (const int*)d_in[3];
    const float* node_emb = (const float*)d_in[4];
    const float* edge_emb = (const float*)d_in[5];
    const float* enc_w  = (const float*)d_in[6];
    const float* enc_b  = (const float*)d_in[7];
    const float* pre_w  = (const float*)d_in[8];
    const float* pre_b  = (const float*)d_in[9];
    const float* post_w = (const float*)d_in[10];
    const float* post_b = (const float*)d_in[11];
    const float* lin_w  = (const float*)d_in[12];
    const float* lin_b  = (const float*)d_in[13];
    const float* bn_g   = (const float*)d_in[14];
    const float* bn_b   = (const float*)d_in[15];
    const float* w1     = (const float*)d_in[16];
    const float* b1     = (const float*)d_in[17];
    const float* w2     = (const float*)d_in[18];
    const float* b2     = (const float*)d_in[19];
    const float* w3     = (const float*)d_in[20];
    const float* b3     = (const float*)d_in[21];

    char* p = (char*)d_ws;
    auto carve = [&](size_t bytes) -> char* {
        char* r = p;
        p += ((bytes + 255) & ~(size_t)255);
        return r;
    };
    __hip_bfloat16* AB = (__hip_bfloat16*)carve((size_t)NN * 750 * 2);
    float* h   = (float*)carve((size_t)NN * 75 * 4);
    float* z   = (float*)carve((size_t)NN * 75 * 4);
    float* tbl = (float*)carve(1500 * 4);
    int* deg    = (int*)carve(NN * 4);
    int* rowptr = (int*)carve((NN + 1) * 4);
    int* fill   = (int*)carve(NN * 4);
    int* csr    = (int*)carve(NE * 4);
    float* bnsum = (float*)carve(150 * 4);
    float* hg    = (float*)carve((size_t)NG * 75 * 4);

    hipMemsetAsync(deg, 0, NN * 4, stream);
    hipMemsetAsync(fill, 0, NN * 4, stream);
    hipMemsetAsync(hg, 0, (size_t)NG * 75 * 4, stream);

    k_deg<<<(NE + 255) / 256, 256, 0, stream>>>(ei + NE, deg);
    k_scan<<<1, 1024, 0, stream>>>(deg, rowptr);
    k_scatter<<<(NE + 255) / 256, 256, 0, stream>>>(ei, ei + NE, eattr, rowptr, fill, csr);
    k_h0<<<(NN * 75 + 255) / 256, 256, 0, stream>>>(x, node_emb, h);

    for (int l = 0; l < NL; l++) {
        k_tbl<<<1, 384, 0, stream>>>(edge_emb, enc_w, enc_b, pre_w, pre_b, l, tbl, bnsum);
        k_preab<<<dim3((NN + 31) / 32, 6), 256, 0, stream>>>(h, pre_w, l, AB);
        k_fused<<<NN / 8, 320, 0, stream>>>(AB, h, tbl, rowptr, csr, post_w, post_b, lin_w, lin_b, l, z, bnsum);
        k_bn<<<(NN * 75 + 255) / 256, 256, 0, stream>>>(z, bnsum, bn_g, bn_b, l, h);
    }

    k_pool<<<(NN * 75 + 255) / 256, 256, 0, stream>>>(h, batch, hg);
    k_mlp<<<NG, 64, 0, stream>>>(hg, w1, b1, w2, b2, w3, b3, (float*)d_out);
}

// Round 2
// 4528.945 us; speedup vs baseline: 1.3668x; 1.3668x over previous
//
#include <hip/hip_runtime.h>
#include <hip/hip_bf16.h>
#include <float.h>
#include <math.h>

#define NN 30000
#define NE 70000
#define NG 1024
#define NT 5
#define FI 75
#define NL 4

// AVG_DEG_LOG = (100*ln2 + 400*ln3 + 300*ln4 + 50*ln5)/850
#define AMP_DENOM 1.1824939264481302f

// ---------------- CSR build ----------------
__global__ __launch_bounds__(256) void k_deg(const int* __restrict__ dst, int* __restrict__ deg) {
    int e = blockIdx.x * 256 + threadIdx.x;
    if (e < NE) atomicAdd(&deg[dst[e]], 1);
}

__global__ __launch_bounds__(1024) void k_scan(const int* __restrict__ deg, int* __restrict__ rowptr) {
    __shared__ int wsum[16];
    __shared__ int s_carry;
    int tid = threadIdx.x;
    int lane = tid & 63, wv = tid >> 6;
    if (tid == 0) s_carry = 0;
    __syncthreads();
    for (int base = 0; base < NN; base += 1024) {
        int i = base + tid;
        int v = (i < NN) ? deg[i] : 0;
        int x = v;
        #pragma unroll
        for (int off = 1; off < 64; off <<= 1) {
            int t = __shfl_up(x, off);
            if (lane >= off) x += t;
        }
        if (lane == 63) wsum[wv] = x;
        __syncthreads();
        if (tid < 16) {
            int y = wsum[tid];
            #pragma unroll
            for (int off = 1; off < 16; off <<= 1) {
                int t = __shfl_up(y, off);
                if (tid >= off) y += t;
            }
            wsum[tid] = y;
        }
        __syncthreads();
        int wbase = ((wv > 0) ? wsum[wv - 1] : 0) + s_carry;
        if (i < NN) rowptr[i] = wbase + x - v;
        int tot = wsum[15];
        __syncthreads();
        if (tid == 0) s_carry += tot;
    }
    __syncthreads();
    if (tid == 0) rowptr[NN] = s_carry;
}

__global__ __launch_bounds__(256) void k_scatter(const int* __restrict__ src, const int* __restrict__ dst,
                                                 const int* __restrict__ attr, const int* __restrict__ rowptr,
                                                 int* __restrict__ fill, int* __restrict__ csr) {
    int e = blockIdx.x * 256 + threadIdx.x;
    if (e < NE) {
        int d = dst[e];
        int pos = rowptr[d] + atomicAdd(&fill[d], 1);
        csr[pos] = src[e] | (attr[e] << 20);
    }
}

// ---------------- embedding ----------------
__global__ __launch_bounds__(256) void k_h0(const int* __restrict__ x, const float* __restrict__ emb,
                                            float* __restrict__ h) {
    int idx = blockIdx.x * 256 + threadIdx.x;
    if (idx < NN * FI) {
        int n = idx / FI, f = idx % FI;
        h[idx] = emb[x[n] * FI + f];
    }
}

// ---------------- per-layer edge-type table (4 x 375), also zeros BN sums ----------------
__global__ __launch_bounds__(384) void k_tbl(const float* __restrict__ edge_emb, const float* __restrict__ enc_w,
                                             const float* __restrict__ enc_b, const float* __restrict__ pre_w,
                                             const float* __restrict__ pre_b, int l,
                                             float* __restrict__ tbl, float* __restrict__ bnsum) {
    __shared__ float e4[4][FI];
    int tid = threadIdx.x;
    if (tid < 150) bnsum[tid] = 0.0f;
    if (tid < 300) {
        int a = tid / FI, f = tid % FI;
        float acc = enc_b[l * FI + f];
        for (int k = 0; k < 50; k++)
            acc += edge_emb[a * 50 + k] * enc_w[(l * 50 + k) * FI + f];
        e4[a][f] = acc;
    }
    __syncthreads();
    for (int idx = tid; idx < 4 * 375; idx += 384) {
        int a = idx / 375, c = idx % 375;
        int t = c / FI, o = c % FI;
        const float* wp = pre_w + ((size_t)(l * NT + t) * 225 + 150) * FI + o;
        float acc = pre_b[(l * NT + t) * FI + o];
        for (int f = 0; f < FI; f++)
            acc += e4[a][f] * wp[f * FI];
        tbl[idx] = acc;
    }
}

// ---------------- AB = h @ [Wdst | Wsrc]  (M=30000, K=75, N=750) -> bf16 ----------------
__global__ __launch_bounds__(256) void k_preab(const float* __restrict__ h, const float* __restrict__ pre_w,
                                               int l, __hip_bfloat16* __restrict__ AB) {
    __shared__ __align__(16) float sh[32][76];
    __shared__ __align__(16) float sw[75][132];
    int tid = threadIdx.x;
    int bm = blockIdx.x * 32;
    int bn = blockIdx.y * 128;

    for (int idx = tid; idx < 75 * 128; idx += 256) {
        int k = idx >> 7, jj = idx & 127;
        int j = bn + jj;
        float w = 0.0f;
        if (j < 750) {
            int jm = (j < 375) ? j : (j - 375);
            int t = jm / FI, o = jm % FI;
            int row = (j < 375) ? k : (75 + k);
            w = pre_w[((size_t)(l * NT + t) * 225 + row) * FI + o];
        }
        sw[k][jj] = w;
    }
    for (int idx = tid; idx < 32 * 75; idx += 256) {
        int r = idx / 75, f = idx % 75;
        int n = bm + r;
        sh[r][f] = (n < NN) ? h[n * FI + f] : 0.0f;
    }
    __syncthreads();

    int tx = tid & 31, ty = tid >> 5;
    float acc[4][4] = {};
    for (int k = 0; k < 75; k++) {
        float4 bv = *reinterpret_cast<const float4*>(&sw[k][tx * 4]);
        float a0 = sh[ty * 4 + 0][k], a1 = sh[ty * 4 + 1][k];
        float a2 = sh[ty * 4 + 2][k], a3 = sh[ty * 4 + 3][k];
        acc[0][0] += a0 * bv.x; acc[0][1] += a0 * bv.y; acc[0][2] += a0 * bv.z; acc[0][3] += a0 * bv.w;
        acc[1][0] += a1 * bv.x; acc[1][1] += a1 * bv.y; acc[1][2] += a1 * bv.z; acc[1][3] += a1 * bv.w;
        acc[2][0] += a2 * bv.x; acc[2][1] += a2 * bv.y; acc[2][2] += a2 * bv.z; acc[2][3] += a2 * bv.w;
        acc[3][0] += a3 * bv.x; acc[3][1] += a3 * bv.y; acc[3][2] += a3 * bv.z; acc[3][3] += a3 * bv.w;
    }
    for (int i = 0; i < 4; i++) {
        int n = bm + ty * 4 + i;
        if (n >= NN) continue;
        for (int j = 0; j < 4; j++) {
            int col = bn + tx * 4 + j;
            if (col < 750) AB[(size_t)n * 750 + col] = __float2bfloat16(acc[i][j]);
        }
    }
}

// ---------------- fused: aggregate + post-NN + lin + BN partials ----------------
__global__ __launch_bounds__(320) void k_fused(const __hip_bfloat16* __restrict__ AB, const float* __restrict__ h,
                                               const float* __restrict__ tbl, const int* __restrict__ rowptr,
                                               const int* __restrict__ csr, const float* __restrict__ post_w,
                                               const float* __restrict__ post_b, const float* __restrict__ lin_w,
                                               const float* __restrict__ lin_b, int l,
                                               float* __restrict__ z, float* __restrict__ bnsum) {
    __shared__ float s_agg[8][1505];
    __shared__ float s_h[8][76];
    __shared__ float s_y[8][81];
    __shared__ __align__(16) float s_buf[6000];   // union: tbl(1500) | 5 wave-regions of 1200 | lin 75x80
    __shared__ float s_amp[8], s_inv[8];

    int tid = threadIdx.x;
    int n0 = blockIdx.x * 8;

    for (int idx = tid; idx < 1500; idx += 320) s_buf[idx] = tbl[idx];
    for (int idx = tid; idx < 600; idx += 320) {
        int i = idx / 75, f = idx % 75;
        s_h[i][f] = h[(n0 + i) * FI + f];
    }
    if (tid < 8) {
        int n = n0 + tid;
        int dg = rowptr[n + 1] - rowptr[n];
        float cnt = fmaxf((float)dg, 1.0f);
        float ampv = logf(cnt + 1.0f) * (1.0f / AMP_DENOM);
        s_amp[tid] = ampv;
        s_inv[tid] = 1.0f / ampv;
    }
    __syncthreads();

    // phase 1: stats over v = B[src] + tbl[attr]; then shift by A (std shift-invariant)
    {
        int i = tid / 40, fp = tid % 40;
        int n = n0 + i;
        int base = rowptr[n];
        int dg = rowptr[n + 1] - base;
        for (int f = fp; f < 375; f += 40) {
            float sum = 0.0f, ss = 0.0f, mn = FLT_MAX, mx = -FLT_MAX;
            for (int k = 0; k < dg; k++) {
                int pk = csr[base + k];
                int s = pk & 0xFFFFF;
                int a = pk >> 20;
                float v = __bfloat162float(AB[(size_t)s * 750 + 375 + f]) + s_buf[a * 375 + f];
                sum += v; ss += v * v;
                mn = fminf(mn, v); mx = fmaxf(mx, v);
            }
            int t = f / 75, of = f % 75;
            int c = t * 300 + of;
            if (dg > 0) {
                float Af = __bfloat162float(AB[(size_t)n * 750 + f]);
                float cnt = (float)dg;
                float mv = sum / cnt;
                float var = ss / cnt - mv * mv;
                s_agg[i][c]       = Af + mv;
                s_agg[i][c + 75]  = Af + mn;
                s_agg[i][c + 150] = Af + mx;
                s_agg[i][c + 225] = sqrtf(fmaxf(var, 0.0f) + 1e-5f);
            } else {
                s_agg[i][c] = 0.0f; s_agg[i][c + 75] = 0.0f; s_agg[i][c + 150] = 0.0f;
                s_agg[i][c + 225] = 0.0031622776601683794f;  // sqrt(1e-5)
            }
        }
    }
    __syncthreads();

    // phase 2: one wave per tower; weights staged through wave-private LDS chunks.
    {
        int lane = tid & 63;
        int w = tid >> 6;                 // wave = tower (5 waves)
        int ni = lane & 7;                // node within block
        int op = lane >> 3;               // output pair 0..7
        int o0 = 2 * op, o1 = o0 + 1;
        bool has1 = (op < 7);             // o1 < 15
        float* wbuf = s_buf + w * 1200;   // [3][25][16]
        const float* twp = post_w + (size_t)(l * NT + w) * 975 * 15;
        float amp = s_amp[ni], inv = s_inv[ni];
        const float* aggrow = &s_agg[ni][w * 300];
        float a1a = 0, a1b = 0, a2a = 0, a2b = 0, a3a = 0, a3b = 0, aha = 0, ahb = 0;

        for (int c = 0; c < 12; c++) {
            #pragma unroll
            for (int s = 0; s < 3; s++) {
                const float* gsrc = twp + (75 + s * 300 + c * 25) * 15;
                for (int e = lane; e < 375; e += 64) {
                    int r = e / 15, col = e - r * 15;
                    wbuf[s * 400 + r * 16 + col] = gsrc[e];
                }
            }
            __syncthreads();
            #pragma unroll 5
            for (int k = 0; k < 25; k++) {
                float av = aggrow[c * 25 + k];
                float2 w1 = *reinterpret_cast<const float2*>(&wbuf[          k * 16 + o0]);
                float2 w2 = *reinterpret_cast<const float2*>(&wbuf[  400 +   k * 16 + o0]);
                float2 w3 = *reinterpret_cast<const float2*>(&wbuf[  800 +   k * 16 + o0]);
                a1a += av * w1.x; a1b += av * w1.y;
                a2a += av * w2.x; a2b += av * w2.y;
                a3a += av * w3.x; a3b += av * w3.y;
            }
            __syncthreads();
        }
        for (int c = 0; c < 3; c++) {
            const float* gsrc = twp + (c * 25) * 15;
            for (int e = lane; e < 375; e += 64) {
                int r = e / 15, col = e - r * 15;
                wbuf[r * 16 + col] = gsrc[e];
            }
            __syncthreads();
            #pragma unroll 5
            for (int k = 0; k < 25; k++) {
                float hv = s_h[ni][c * 25 + k];
                float2 w0 = *reinterpret_cast<const float2*>(&wbuf[k * 16 + o0]);
                aha += hv * w0.x; ahb += hv * w0.y;
            }
            __syncthreads();
        }
        float outa = aha + a1a + amp * a2a + inv * a3a + post_b[(l * NT + w) * 15 + o0];
        s_y[ni][w * 15 + o0] = outa;
        if (has1) {
            float outb = ahb + a1b + amp * a2b + inv * a3b + post_b[(l * NT + w) * 15 + o1];
            s_y[ni][w * 15 + o1] = outb;
        }
    }
    __syncthreads();

    // phase 3: lin via LDS-staged lin_w + BN partials via shuffle reduce
    for (int idx = tid; idx < 5625; idx += 320) {
        int k = idx / 75, c = idx - k * 75;
        s_buf[k * 80 + c] = lin_w[(size_t)l * 5625 + idx];
    }
    __syncthreads();
    for (int pass = 0; pass < 2; pass++) {
        int idx = tid + pass * 320;
        if (idx < 600) {
            int ni = idx & 7, c = idx >> 3;
            float acc = lin_b[l * 75 + c];
            #pragma unroll 5
            for (int k = 0; k < 75; k++)
                acc += s_y[ni][k] * s_buf[k * 80 + c];
            z[(size_t)(n0 + ni) * 75 + c] = acc;
            float v1 = acc, v2 = acc * acc;
            #pragma unroll
            for (int off = 1; off < 8; off <<= 1) {
                v1 += __shfl_xor(v1, off);
                v2 += __shfl_xor(v2, off);
            }
            if (ni == 0) {
                atomicAdd(&bnsum[c], v1);
                atomicAdd(&bnsum[75 + c], v2);
            }
        }
    }
}

// ---------------- BN + ReLU ----------------
__global__ __launch_bounds__(256) void k_bn(const float* __restrict__ z, const float* __restrict__ bnsum,
                                            const float* __restrict__ bn_g, const float* __restrict__ bn_b,
                                            int l, float* __restrict__ h) {
    int idx = blockIdx.x * 256 + threadIdx.x;
    if (idx < NN * 75) {
        int c = idx % 75;
        float mu = bnsum[c] * (1.0f / NN);
        float msq = bnsum[75 + c] * (1.0f / NN);
        float var = msq - mu * mu;
        float v = (z[idx] - mu) * rsqrtf(var + 1e-5f) * bn_g[l * 75 + c] + bn_b[l * 75 + c];
        h[idx] = fmaxf(v, 0.0f);
    }
}

// ---------------- pooling + MLP ----------------
__global__ __launch_bounds__(256) void k_pool(const float* __restrict__ h, const int* __restrict__ batch,
                                              float* __restrict__ hg) {
    int idx = blockIdx.x * 256 + threadIdx.x;
    if (idx < NN * 75) {
        int n = idx / 75, f = idx % 75;
        atomicAdd(&hg[batch[n] * 75 + f], h[idx]);
    }
}

__global__ __launch_bounds__(64) void k_mlp(const float* __restrict__ hg,
                                            const float* __restrict__ w1, const float* __restrict__ b1,
                                            const float* __restrict__ w2, const float* __restrict__ b2,
                                            const float* __restrict__ w3, const float* __restrict__ b3,
                                            float* __restrict__ out) {
    __shared__ float zin[75], z1[50], z2[25];
    int g = blockIdx.x, tid = threadIdx.x;
    for (int k = tid; k < 75; k += 64) zin[k] = hg[g * 75 + k];
    __syncthreads();
    if (tid < 50) {
        float acc = b1[tid];
        for (int k = 0; k < 75; k++) acc += zin[k] * w1[k * 50 + tid];
        z1[tid] = fmaxf(acc, 0.0f);
    }
    __syncthreads();
    if (tid < 25) {
        float acc = b2[tid];
        for (int k = 0; k < 50; k++) acc += z1[k] * w2[k * 25 + tid];
        z2[tid] = fmaxf(acc, 0.0f);
    }
    __syncthreads();
    if (tid == 0) {
        float acc = b3[0];
        for (int k = 0; k < 25; k++) acc += z2[k] * w3[k];
        out[g] = acc;
    }
}

extern "C" void kernel_launch(void* const* d_in, const int* in_sizes, int n_in,
                              void* d_out, int out_size, void* d_ws, size_t ws_size,
                              hipStream_t stream) {
    const int* x        = (const int*)d_in[0];
    const int* ei       = (const int*)d_in[1];
    const int* eattr    = (const int*)d_in[2];
    const int* batch    = (const int*)d_in[3];
    const float* node_emb = (const float*)d_in[4];
    const float* edge_emb = (const float*)d_in[5];
    const float* enc_w  = (const float*)d_in[6];
    const float* enc_b  = (const float*)d_in[7];
    const float* pre_w  = (const float*)d_in[8];
    const float* pre_b  = (const float*)d_in[9];
    const float* post_w = (const float*)d_in[10];
    const float* post_b = (const float*)d_in[11];
    const float* lin_w  = (const float*)d_in[12];
    const float* lin_b  = (const float*)d_in[13];
    const float* bn_g   = (const float*)d_in[14];
    const float* bn_b   = (const float*)d_in[15];
    const float* w1     = (const float*)d_in[16];
    const float* b1     = (const float*)d_in[17];
    const float* w2     = (const float*)d_in[18];
    const float* b2     = (const float*)d_in[19];
    const float* w3     = (const float*)d_in[20];
    const float* b3     = (const float*)d_in[21];

    char* p = (char*)d_ws;
    auto carve = [&](size_t bytes) -> char* {
        char* r = p;
        p += ((bytes + 255) & ~(size_t)255);
        return r;
    };
    __hip_bfloat16* AB = (__hip_bfloat16*)carve((size_t)NN * 750 * 2);
    float* h   = (float*)carve((size_t)NN * 75 * 4);
    float* z   = (float*)carve((size_t)NN * 75 * 4);
    float* tbl = (float*)carve(1500 * 4);
    int* deg    = (int*)carve(NN * 4);
    int* rowptr = (int*)carve((NN + 1) * 4);
    int* fill   = (int*)carve(NN * 4);
    int* csr    = (int*)carve(NE * 4);
    float* bnsum = (float*)carve(150 * 4);
    float* hg    = (float*)carve((size_t)NG * 75 * 4);

    hipMemsetAsync(deg, 0, NN * 4, stream);
    hipMemsetAsync(fill, 0, NN * 4, stream);
    hipMemsetAsync(hg, 0, (size_t)NG * 75 * 4, stream);

    k_deg<<<(NE + 255) / 256, 256, 0, stream>>>(ei + NE, deg);
    k_scan<<<1, 1024, 0, stream>>>(deg, rowptr);
    k_scatter<<<(NE + 255) / 256, 256, 0, stream>>>(ei, ei + NE, eattr, rowptr, fill, csr);
    k_h0<<<(NN * 75 + 255) / 256, 256, 0, stream>>>(x, node_emb, h);

    for (int l = 0; l < NL; l++) {
        k_tbl<<<1, 384, 0, stream>>>(edge_emb, enc_w, enc_b, pre_w, pre_b, l, tbl, bnsum);
        k_preab<<<dim3((NN + 31) / 32, 6), 256, 0, stream>>>(h, pre_w, l, AB);
        k_fused<<<NN / 8, 320, 0, stream>>>(AB, h, tbl, rowptr, csr, post_w, post_b, lin_w, lin_b, l, z, bnsum);
        k_bn<<<(NN * 75 + 255) / 256, 256, 0, stream>>>(z, bnsum, bn_g, bn_b, l, h);
    }

    k_pool<<<(NN * 75 + 255) / 256, 256, 0, stream>>>(h, batch, hg);
    k_mlp<<<NG, 64, 0, stream>>>(hg, w1, b1, w2, b2, w3, b3, (float*)d_out);
}

// Round 3
// 1563.374 us; speedup vs baseline: 3.9594x; 2.8969x over previous
//
#include <hip/hip_runtime.h>
#include <hip/hip_bf16.h>
#include <float.h>
#include <math.h>

#define NN 30000
#define NE 70000
#define NG 1024
#define NT 5
#define FI 75
#define NL 4

// AVG_DEG_LOG = (100*ln2 + 400*ln3 + 300*ln4 + 50*ln5)/850
#define AMP_DENOM 1.1824939264481302f

// ABH: [NN][832] bf16 : cols 0..374 = A (h@Wdst), 375..749 = B (h@Wsrc),
//                        750..824 = hterm (h@post_w rows 0..74), 825..831 pad
#define ABW 832
// AGG: [NN][1536] bf16 : per tower t (5): 304 = 4 stats x 76 (75 + zero pad)
#define AGW 1536
// Wpack per (l,t): [76 j2][3 s][16 o][4 p] f32  (k = j2*4+p; sigma=k/76, of=k%76)
#define WPT 14592

__device__ __forceinline__ float bf2f(unsigned short u) {
    return __uint_as_float(((unsigned int)u) << 16);
}
__device__ __forceinline__ unsigned short f2bf(float f) {
    __hip_bfloat16 h = __float2bfloat16(f);
    return *reinterpret_cast<unsigned short*>(&h);
}

// ---------------- CSR build ----------------
__global__ __launch_bounds__(256) void k_deg(const int* __restrict__ dst, int* __restrict__ deg) {
    int e = blockIdx.x * 256 + threadIdx.x;
    if (e < NE) atomicAdd(&deg[dst[e]], 1);
}

__global__ __launch_bounds__(1024) void k_scan(const int* __restrict__ deg, int* __restrict__ rowptr) {
    __shared__ int wsum[16];
    __shared__ int s_carry;
    int tid = threadIdx.x;
    int lane = tid & 63, wv = tid >> 6;
    if (tid == 0) s_carry = 0;
    __syncthreads();
    for (int base = 0; base < NN; base += 1024) {
        int i = base + tid;
        int v = (i < NN) ? deg[i] : 0;
        int x = v;
        #pragma unroll
        for (int off = 1; off < 64; off <<= 1) {
            int t = __shfl_up(x, off);
            if (lane >= off) x += t;
        }
        if (lane == 63) wsum[wv] = x;
        __syncthreads();
        if (tid < 16) {
            int y = wsum[tid];
            #pragma unroll
            for (int off = 1; off < 16; off <<= 1) {
                int t = __shfl_up(y, off);
                if (tid >= off) y += t;
            }
            wsum[tid] = y;
        }
        __syncthreads();
        int wbase = ((wv > 0) ? wsum[wv - 1] : 0) + s_carry;
        if (i < NN) rowptr[i] = wbase + x - v;
        int tot = wsum[15];
        __syncthreads();
        if (tid == 0) s_carry += tot;
    }
    __syncthreads();
    if (tid == 0) rowptr[NN] = s_carry;
}

__global__ __launch_bounds__(256) void k_scatter(const int* __restrict__ src, const int* __restrict__ dst,
                                                 const int* __restrict__ attr, const int* __restrict__ rowptr,
                                                 int* __restrict__ fill, int* __restrict__ csr) {
    int e = blockIdx.x * 256 + threadIdx.x;
    if (e < NE) {
        int d = dst[e];
        int pos = rowptr[d] + atomicAdd(&fill[d], 1);
        csr[pos] = src[e] | (attr[e] << 20);
    }
}

// amp/inv per node (degree-only, layer-invariant)
__global__ __launch_bounds__(256) void k_amp(const int* __restrict__ rowptr,
                                             float* __restrict__ amp, float* __restrict__ inv) {
    int n = blockIdx.x * 256 + threadIdx.x;
    if (n < NN) {
        int dg = rowptr[n + 1] - rowptr[n];
        float cnt = fmaxf((float)dg, 1.0f);
        float a = logf(cnt + 1.0f) * (1.0f / AMP_DENOM);
        amp[n] = a;
        inv[n] = 1.0f / a;
    }
}

// ---------------- embedding ----------------
__global__ __launch_bounds__(256) void k_h0(const int* __restrict__ x, const float* __restrict__ emb,
                                            float* __restrict__ h) {
    int idx = blockIdx.x * 256 + threadIdx.x;
    if (idx < NN * FI) {
        int n = idx / FI, f = idx % FI;
        h[idx] = emb[x[n] * FI + f];
    }
}

// ---------------- weight pre-pack (all layers, once) ----------------
__global__ __launch_bounds__(256) void k_wprep(const float* __restrict__ post_w, float* __restrict__ Wpack) {
    int idx = blockIdx.x * 256 + threadIdx.x;
    if (idx >= NL * NT * WPT) return;
    int p = idx & 3;
    int o = (idx >> 2) & 15;
    int s = (idx >> 6) % 3;
    int rest = idx / 192;          // ((l*5+t)*76 + j2)
    int j2 = rest % 76;
    int lt = rest / 76;            // l*5+t
    int k = j2 * 4 + p;
    int sg = k / 76;
    int of = k - sg * 76;
    float val = 0.0f;
    if (of < 75 && o < 15)
        val = post_w[((size_t)lt * 975 + 75 + s * 300 + sg * 75 + of) * 15 + o];
    Wpack[idx] = val;
}

// ---------------- per-layer edge-type table (4 x 375), also zeros BN sums ----------------
__global__ __launch_bounds__(384) void k_tbl(const float* __restrict__ edge_emb, const float* __restrict__ enc_w,
                                             const float* __restrict__ enc_b, const float* __restrict__ pre_w,
                                             const float* __restrict__ pre_b, int l,
                                             float* __restrict__ tbl, float* __restrict__ bnsum) {
    __shared__ float e4[4][FI];
    int tid = threadIdx.x;
    if (tid < 150) bnsum[tid] = 0.0f;
    if (tid < 300) {
        int a = tid / FI, f = tid % FI;
        float acc = enc_b[l * FI + f];
        for (int k = 0; k < 50; k++)
            acc += edge_emb[a * 50 + k] * enc_w[(l * 50 + k) * FI + f];
        e4[a][f] = acc;
    }
    __syncthreads();
    for (int idx = tid; idx < 4 * 375; idx += 384) {
        int a = idx / 375, c = idx % 375;
        int t = c / FI, o = c % FI;
        const float* wp = pre_w + ((size_t)(l * NT + t) * 225 + 150) * FI + o;
        float acc = pre_b[(l * NT + t) * FI + o];
        for (int f = 0; f < FI; f++)
            acc += e4[a][f] * wp[f * FI];
        tbl[idx] = acc;
    }
}

// ---------------- ABH = h @ [Wdst | Wsrc | W0cat]  (M=30000, K=75, N=825->832) -> bf16 ----------------
__global__ __launch_bounds__(256) void k_preab(const float* __restrict__ h, const float* __restrict__ pre_w,
                                               const float* __restrict__ post_w, int l,
                                               __hip_bfloat16* __restrict__ ABH) {
    __shared__ __align__(16) float sh[32][76];
    __shared__ __align__(16) float sw[75][132];
    int tid = threadIdx.x;
    int bm = blockIdx.x * 32;
    int bn = blockIdx.y * 128;

    for (int idx = tid; idx < 75 * 128; idx += 256) {
        int k = idx >> 7, jj = idx & 127;
        int j = bn + jj;
        float w = 0.0f;
        if (j < 750) {
            int jm = (j < 375) ? j : (j - 375);
            int t = jm / FI, o = jm % FI;
            int row = (j < 375) ? k : (75 + k);
            w = pre_w[((size_t)(l * NT + t) * 225 + row) * FI + o];
        } else if (j < 825) {
            int c = j - 750;
            int t = c / 15, o = c % 15;
            w = post_w[((size_t)(l * NT + t) * 975 + k) * 15 + o];
        }
        sw[k][jj] = w;
    }
    for (int idx = tid; idx < 32 * 75; idx += 256) {
        int r = idx / 75, f = idx % 75;
        int n = bm + r;
        sh[r][f] = (n < NN) ? h[n * FI + f] : 0.0f;
    }
    __syncthreads();

    int tx = tid & 31, ty = tid >> 5;
    float acc[4][4] = {};
    for (int k = 0; k < 75; k++) {
        float4 bv = *reinterpret_cast<const float4*>(&sw[k][tx * 4]);
        float a0 = sh[ty * 4 + 0][k], a1 = sh[ty * 4 + 1][k];
        float a2 = sh[ty * 4 + 2][k], a3 = sh[ty * 4 + 3][k];
        acc[0][0] += a0 * bv.x; acc[0][1] += a0 * bv.y; acc[0][2] += a0 * bv.z; acc[0][3] += a0 * bv.w;
        acc[1][0] += a1 * bv.x; acc[1][1] += a1 * bv.y; acc[1][2] += a1 * bv.z; acc[1][3] += a1 * bv.w;
        acc[2][0] += a2 * bv.x; acc[2][1] += a2 * bv.y; acc[2][2] += a2 * bv.z; acc[2][3] += a2 * bv.w;
        acc[3][0] += a3 * bv.x; acc[3][1] += a3 * bv.y; acc[3][2] += a3 * bv.z; acc[3][3] += a3 * bv.w;
    }
    for (int i = 0; i < 4; i++) {
        int n = bm + ty * 4 + i;
        if (n >= NN) continue;
        for (int j = 0; j < 4; j++) {
            int col = bn + tx * 4 + j;
            if (col < ABW) ABH[(size_t)n * ABW + col] = __float2bfloat16(acc[i][j]);
        }
    }
}

// ---------------- gather: per-node stats -> AGG bf16 ----------------
__global__ __launch_bounds__(256) void k_gather(const __hip_bfloat16* __restrict__ ABH,
                                                const float* __restrict__ tbl,
                                                const int* __restrict__ rowptr, const int* __restrict__ csr,
                                                unsigned short* __restrict__ AGG) {
    __shared__ float s_tbl[1500];
    int tid = threadIdx.x;
    for (int i = tid; i < 1500; i += 256) s_tbl[i] = tbl[i];
    __syncthreads();

    int w = tid >> 6, l = tid & 63;
    int n = blockIdx.x * 4 + w;
    int base = rowptr[n];
    int dg = rowptr[n + 1] - base;

    float sum[6], ss[6], mn[6], mx[6];
    #pragma unroll
    for (int j = 0; j < 6; j++) { sum[j] = 0.f; ss[j] = 0.f; mn[j] = FLT_MAX; mx[j] = -FLT_MAX; }

    const unsigned short* abu = (const unsigned short*)ABH;
    for (int k = 0; k < dg; k++) {
        int pk = csr[base + k];
        int s = pk & 0xFFFFF;
        int a = pk >> 20;
        const unsigned short* bp = abu + (size_t)s * ABW + 375;
        const float* tp = s_tbl + a * 375;
        #pragma unroll
        for (int j = 0; j < 6; j++) {
            int f = l + 64 * j;
            if (f < 375) {
                float v = bf2f(bp[f]) + tp[f];
                sum[j] += v; ss[j] += v * v;
                mn[j] = fminf(mn[j], v); mx[j] = fmaxf(mx[j], v);
            }
        }
    }

    unsigned short* out = AGG + (size_t)n * AGW;
    if (dg > 0) {
        float rc = 1.0f / (float)dg;
        const unsigned short* ap = abu + (size_t)n * ABW;
        #pragma unroll
        for (int j = 0; j < 6; j++) {
            int f = l + 64 * j;
            if (f < 375) {
                int t = f / 75, of = f - t * 75;
                int o = t * 304 + of;
                float Af = bf2f(ap[f]);
                float mean = sum[j] * rc;
                float var = ss[j] * rc - mean * mean;
                out[o]       = f2bf(Af + mean);
                out[o + 76]  = f2bf(Af + mn[j]);
                out[o + 152] = f2bf(Af + mx[j]);
                out[o + 228] = f2bf(sqrtf(fmaxf(var, 0.0f) + 1e-5f));
            }
        }
    } else {
        unsigned short z = 0;
        unsigned short sd = f2bf(0.0031622776601683794f);  // sqrt(1e-5)
        #pragma unroll
        for (int j = 0; j < 6; j++) {
            int f = l + 64 * j;
            if (f < 375) {
                int t = f / 75, of = f - t * 75;
                int o = t * 304 + of;
                out[o] = z; out[o + 76] = z; out[o + 152] = z; out[o + 228] = sd;
            }
        }
    }
    // zero the k-pads (of == 75) : 5 towers x 4 stats
    if (l < 20) out[(l >> 2) * 304 + (l & 3) * 76 + 75] = 0;
}

// ---------------- post: 5 tower-GEMMs + combine + lin + BN partials ----------------
__global__ __launch_bounds__(256) void k_post(const __hip_bfloat16* __restrict__ ABH,
                                              const unsigned int* __restrict__ AGGu,
                                              const float* __restrict__ Wpack,
                                              const float* __restrict__ amp_a, const float* __restrict__ inv_a,
                                              const float* __restrict__ post_b,
                                              const float* __restrict__ lin_w, const float* __restrict__ lin_b,
                                              int l, float* __restrict__ z, float* __restrict__ bnsum) {
    __shared__ __align__(16) float s_w[WPT];        // 58368 B (reused for lin_w)
    __shared__ float s_y[64 * 76];                  // 19456 B
    __shared__ float s_bn[152];

    int tid = threadIdx.x;
    int tx = tid & 15, ty = tid >> 4;
    int n0 = blockIdx.x * 64;
    if (tid < 152) s_bn[tid] = 0.0f;

    int nn[4]; bool nv[4];
    float am[4], iv[4];
    #pragma unroll
    for (int r = 0; r < 4; r++) {
        int n = n0 + ty + r * 16;
        nv[r] = (n < NN);
        nn[r] = nv[r] ? n : (NN - 1);
        am[r] = amp_a[nn[r]];
        iv[r] = inv_a[nn[r]];
    }
    const unsigned short* abu = (const unsigned short*)ABH;

    for (int t = 0; t < NT; t++) {
        // stage packed weights for this tower
        const float4* wsrc = (const float4*)(Wpack + (size_t)(l * NT + t) * WPT);
        float4* wdst = (float4*)s_w;
        for (int i = tid; i < WPT / 4; i += 256) wdst[i] = wsrc[i];
        __syncthreads();

        float p1[4] = {}, p2[4] = {}, p3[4] = {};
        #pragma unroll 2
        for (int j2 = 0; j2 < 76; j2++) {
            const float* wb = s_w + (j2 * 3) * 64 + tx * 4;
            float4 w1 = *reinterpret_cast<const float4*>(wb);
            float4 w2 = *reinterpret_cast<const float4*>(wb + 64);
            float4 w3 = *reinterpret_cast<const float4*>(wb + 128);
            #pragma unroll
            for (int r = 0; r < 4; r++) {
                uint2 u = *reinterpret_cast<const uint2*>(AGGu + (size_t)nn[r] * 768 + t * 152 + j2 * 2);
                float f0 = __uint_as_float(u.x << 16);
                float f1 = __uint_as_float(u.x & 0xFFFF0000u);
                float f2 = __uint_as_float(u.y << 16);
                float f3 = __uint_as_float(u.y & 0xFFFF0000u);
                p1[r] += f0 * w1.x + f1 * w1.y + f2 * w1.z + f3 * w1.w;
                p2[r] += f0 * w2.x + f1 * w2.y + f2 * w2.z + f3 * w2.w;
                p3[r] += f0 * w3.x + f1 * w3.y + f2 * w3.z + f3 * w3.w;
            }
        }
        if (tx < 15) {
            float qb = post_b[(l * NT + t) * 15 + tx];
            #pragma unroll
            for (int r = 0; r < 4; r++) {
                float ht = bf2f(abu[(size_t)nn[r] * ABW + 750 + t * 15 + tx]);
                float y = ht + p1[r] + am[r] * p2[r] + iv[r] * p3[r] + qb;
                s_y[(ty + r * 16) * 76 + t * 15 + tx] = nv[r] ? y : 0.0f;
            }
        }
        __syncthreads();
    }

    // stage lin_w into s_w region: [75][80]
    for (int i = tid; i < 5625; i += 256) {
        int k = i / 75, c = i - k * 75;
        s_w[k * 80 + c] = lin_w[(size_t)l * 5625 + i];
    }
    __syncthreads();

    // lin: thread -> 4 nodes x cols {tx + 16u}
    float acc[4][5];
    #pragma unroll
    for (int r = 0; r < 4; r++)
        #pragma unroll
        for (int u = 0; u < 5; u++) {
            int c = tx + 16 * u;
            acc[r][u] = (c < 75) ? lin_b[l * 75 + c] : 0.0f;
        }
    for (int k = 0; k < 75; k++) {
        float wv[5];
        #pragma unroll
        for (int u = 0; u < 5; u++) {
            int c = tx + 16 * u;
            wv[u] = (c < 75) ? s_w[k * 80 + c] : 0.0f;
        }
        #pragma unroll
        for (int r = 0; r < 4; r++) {
            float yv = s_y[(ty + r * 16) * 76 + k];
            #pragma unroll
            for (int u = 0; u < 5; u++) acc[r][u] += yv * wv[u];
        }
    }

    float b1a[5] = {}, b2a[5] = {};
    #pragma unroll
    for (int r = 0; r < 4; r++) {
        int n = n0 + ty + r * 16;
        #pragma unroll
        for (int u = 0; u < 5; u++) {
            int c = tx + 16 * u;
            if (c < 75 && nv[r]) {
                z[(size_t)n * 75 + c] = acc[r][u];
                b1a[u] += acc[r][u];
                b2a[u] += acc[r][u] * acc[r][u];
            }
        }
    }
    #pragma unroll
    for (int u = 0; u < 5; u++) {
        b1a[u] += __shfl_xor(b1a[u], 16); b1a[u] += __shfl_xor(b1a[u], 32);
        b2a[u] += __shfl_xor(b2a[u], 16); b2a[u] += __shfl_xor(b2a[u], 32);
    }
    if ((tid & 63) < 16) {
        #pragma unroll
        for (int u = 0; u < 5; u++) {
            int c = tx + 16 * u;
            if (c < 75) {
                atomicAdd(&s_bn[c], b1a[u]);
                atomicAdd(&s_bn[76 + c], b2a[u]);
            }
        }
    }
    __syncthreads();
    if (tid < 75) {
        atomicAdd(&bnsum[tid], s_bn[tid]);
        atomicAdd(&bnsum[75 + tid], s_bn[76 + tid]);
    }
}

// ---------------- BN + ReLU ----------------
__global__ __launch_bounds__(256) void k_bn(const float* __restrict__ z, const float* __restrict__ bnsum,
                                            const float* __restrict__ bn_g, const float* __restrict__ bn_b,
                                            int l, float* __restrict__ h) {
    int idx = blockIdx.x * 256 + threadIdx.x;
    if (idx < NN * 75) {
        int c = idx % 75;
        float mu = bnsum[c] * (1.0f / NN);
        float msq = bnsum[75 + c] * (1.0f / NN);
        float var = msq - mu * mu;
        float v = (z[idx] - mu) * rsqrtf(var + 1e-5f) * bn_g[l * 75 + c] + bn_b[l * 75 + c];
        h[idx] = fmaxf(v, 0.0f);
    }
}

// ---------------- pooling + MLP ----------------
__global__ __launch_bounds__(256) void k_pool(const float* __restrict__ h, const int* __restrict__ batch,
                                              float* __restrict__ hg) {
    int idx = blockIdx.x * 256 + threadIdx.x;
    if (idx < NN * 75) {
        int n = idx / 75, f = idx % 75;
        atomicAdd(&hg[batch[n] * 75 + f], h[idx]);
    }
}

__global__ __launch_bounds__(64) void k_mlp(const float* __restrict__ hg,
                                            const float* __restrict__ w1, const float* __restrict__ b1,
                                            const float* __restrict__ w2, const float* __restrict__ b2,
                                            const float* __restrict__ w3, const float* __restrict__ b3,
                                            float* __restrict__ out) {
    __shared__ float zin[75], z1[50], z2[25];
    int g = blockIdx.x, tid = threadIdx.x;
    for (int k = tid; k < 75; k += 64) zin[k] = hg[g * 75 + k];
    __syncthreads();
    if (tid < 50) {
        float acc = b1[tid];
        for (int k = 0; k < 75; k++) acc += zin[k] * w1[k * 50 + tid];
        z1[tid] = fmaxf(acc, 0.0f);
    }
    __syncthreads();
    if (tid < 25) {
        float acc = b2[tid];
        for (int k = 0; k < 50; k++) acc += z1[k] * w2[k * 25 + tid];
        z2[tid] = fmaxf(acc, 0.0f);
    }
    __syncthreads();
    if (tid == 0) {
        float acc = b3[0];
        for (int k = 0; k < 25; k++) acc += z2[k] * w3[k];
        out[g] = acc;
    }
}

extern "C" void kernel_launch(void* const* d_in, const int* in_sizes, int n_in,
                              void* d_out, int out_size, void* d_ws, size_t ws_size,
                              hipStream_t stream) {
    const int* x        = (const int*)d_in[0];
    const int* ei       = (const int*)d_in[1];
    const int* eattr    = (const int*)d_in[2];
    const int* batch    = (const int*)d_in[3];
    const float* node_emb = (const float*)d_in[4];
    const float* edge_emb = (const float*)d_in[5];
    const float* enc_w  = (const float*)d_in[6];
    const float* enc_b  = (const float*)d_in[7];
    const float* pre_w  = (const float*)d_in[8];
    const float* pre_b  = (const float*)d_in[9];
    const float* post_w = (const float*)d_in[10];
    const float* post_b = (const float*)d_in[11];
    const float* lin_w  = (const float*)d_in[12];
    const float* lin_b  = (const float*)d_in[13];
    const float* bn_g   = (const float*)d_in[14];
    const float* bn_b   = (const float*)d_in[15];
    const float* w1     = (const float*)d_in[16];
    const float* b1     = (const float*)d_in[17];
    const float* w2     = (const float*)d_in[18];
    const float* b2     = (const float*)d_in[19];
    const float* w3     = (const float*)d_in[20];
    const float* b3     = (const float*)d_in[21];

    char* p = (char*)d_ws;
    auto carve = [&](size_t bytes) -> char* {
        char* r = p;
        p += ((bytes + 255) & ~(size_t)255);
        return r;
    };
    __hip_bfloat16* ABH = (__hip_bfloat16*)carve((size_t)NN * ABW * 2);
    unsigned short* AGG = (unsigned short*)carve((size_t)NN * AGW * 2);
    float* h     = (float*)carve((size_t)NN * 75 * 4);
    float* z     = (float*)carve((size_t)NN * 75 * 4);
    float* Wpack = (float*)carve((size_t)NL * NT * WPT * 4);
    float* tbl   = (float*)carve(1500 * 4);
    int* deg     = (int*)carve(NN * 4);
    int* rowptr  = (int*)carve((NN + 1) * 4);
    int* fill    = (int*)carve(NN * 4);
    int* csr     = (int*)carve(NE * 4);
    float* bnsum = (float*)carve(150 * 4);
    float* amp_a = (float*)carve(NN * 4);
    float* inv_a = (float*)carve(NN * 4);
    float* hg    = (float*)carve((size_t)NG * 75 * 4);

    hipMemsetAsync(deg, 0, NN * 4, stream);
    hipMemsetAsync(fill, 0, NN * 4, stream);
    hipMemsetAsync(hg, 0, (size_t)NG * 75 * 4, stream);

    k_deg<<<(NE + 255) / 256, 256, 0, stream>>>(ei + NE, deg);
    k_scan<<<1, 1024, 0, stream>>>(deg, rowptr);
    k_scatter<<<(NE + 255) / 256, 256, 0, stream>>>(ei, ei + NE, eattr, rowptr, fill, csr);
    k_amp<<<(NN + 255) / 256, 256, 0, stream>>>(rowptr, amp_a, inv_a);
    k_h0<<<(NN * 75 + 255) / 256, 256, 0, stream>>>(x, node_emb, h);
    k_wprep<<<(NL * NT * WPT + 255) / 256, 256, 0, stream>>>(post_w, Wpack);

    for (int l = 0; l < NL; l++) {
        k_tbl<<<1, 384, 0, stream>>>(edge_emb, enc_w, enc_b, pre_w, pre_b, l, tbl, bnsum);
        k_preab<<<dim3((NN + 31) / 32, 7), 256, 0, stream>>>(h, pre_w, post_w, l, ABH);
        k_gather<<<NN / 4, 256, 0, stream>>>(ABH, tbl, rowptr, csr, AGG);
        k_post<<<(NN + 63) / 64, 256, 0, stream>>>(ABH, (const unsigned int*)AGG, Wpack, amp_a, inv_a,
                                                   post_b, lin_w, lin_b, l, z, bnsum);
        k_bn<<<(NN * 75 + 255) / 256, 256, 0, stream>>>(z, bnsum, bn_g, bn_b, l, h);
    }

    k_pool<<<(NN * 75 + 255) / 256, 256, 0, stream>>>(h, batch, hg);
    k_mlp<<<NG, 64, 0, stream>>>(hg, w1, b1, w2, b2, w3, b3, (float*)d_out);
}

// Round 4
// 1042.510 us; speedup vs baseline: 5.9377x; 1.4996x over previous
//
#include <hip/hip_runtime.h>
#include <hip/hip_bf16.h>
#include <float.h>
#include <math.h>

#define NN 30000
#define NE 70000
#define NG 1024
#define NT 5
#define FI 75
#define NL 4

// AVG_DEG_LOG = (100*ln2 + 400*ln3 + 300*ln4 + 50*ln5)/850
#define AMP_DENOM 1.1824939264481302f

// ABH: [NN][832] bf16 : cols 0..374 = A (h@Wdst), 375..749 = B (h@Wsrc),
//                        750..824 = hterm (h@post_w rows 0..74), 825..831 pad
#define ABW 832
// AGG: [NN][1536] bf16 : per tower t (5): 304 = 4 stats x 76 (75 + zero pad)
#define AGW 1536
// Wpack per (l,t): [76 j2][3 s][16 o][4 p] f32  (k = j2*4+p; sigma=k/76, of=k%76)
#define WPT 14592
// hb: [NN][96] bf16, cols 75..95 zero.  WcatT: [NL][832][96] bf16, k rows 75..95 zero.
#define HBW 96

typedef __attribute__((ext_vector_type(8))) short bf16x8;
typedef __attribute__((ext_vector_type(4))) float f32x4;

__device__ __forceinline__ float bf2f(unsigned short u) {
    return __uint_as_float(((unsigned int)u) << 16);
}
__device__ __forceinline__ unsigned short f2bf(float f) {
    __hip_bfloat16 h = __float2bfloat16(f);
    return *reinterpret_cast<unsigned short*>(&h);
}

// ---------------- CSR build ----------------
__global__ __launch_bounds__(256) void k_deg(const int* __restrict__ dst, int* __restrict__ deg) {
    int e = blockIdx.x * 256 + threadIdx.x;
    if (e < NE) atomicAdd(&deg[dst[e]], 1);
}

__global__ __launch_bounds__(1024) void k_scan(const int* __restrict__ deg, int* __restrict__ rowptr) {
    __shared__ int wsum[16];
    __shared__ int s_carry;
    int tid = threadIdx.x;
    int lane = tid & 63, wv = tid >> 6;
    if (tid == 0) s_carry = 0;
    __syncthreads();
    for (int base = 0; base < NN; base += 1024) {
        int i = base + tid;
        int v = (i < NN) ? deg[i] : 0;
        int x = v;
        #pragma unroll
        for (int off = 1; off < 64; off <<= 1) {
            int t = __shfl_up(x, off);
            if (lane >= off) x += t;
        }
        if (lane == 63) wsum[wv] = x;
        __syncthreads();
        if (tid < 16) {
            int y = wsum[tid];
            #pragma unroll
            for (int off = 1; off < 16; off <<= 1) {
                int t = __shfl_up(y, off);
                if (tid >= off) y += t;
            }
            wsum[tid] = y;
        }
        __syncthreads();
        int wbase = ((wv > 0) ? wsum[wv - 1] : 0) + s_carry;
        if (i < NN) rowptr[i] = wbase + x - v;
        int tot = wsum[15];
        __syncthreads();
        if (tid == 0) s_carry += tot;
    }
    __syncthreads();
    if (tid == 0) rowptr[NN] = s_carry;
}

__global__ __launch_bounds__(256) void k_scatter(const int* __restrict__ src, const int* __restrict__ dst,
                                                 const int* __restrict__ attr, const int* __restrict__ rowptr,
                                                 int* __restrict__ fill, int* __restrict__ csr) {
    int e = blockIdx.x * 256 + threadIdx.x;
    if (e < NE) {
        int d = dst[e];
        int pos = rowptr[d] + atomicAdd(&fill[d], 1);
        csr[pos] = src[e] | (attr[e] << 20);
    }
}

// amp/inv per node (degree-only, layer-invariant)
__global__ __launch_bounds__(256) void k_amp(const int* __restrict__ rowptr,
                                             float* __restrict__ amp, float* __restrict__ inv) {
    int n = blockIdx.x * 256 + threadIdx.x;
    if (n < NN) {
        int dg = rowptr[n + 1] - rowptr[n];
        float cnt = fmaxf((float)dg, 1.0f);
        float a = logf(cnt + 1.0f) * (1.0f / AMP_DENOM);
        amp[n] = a;
        inv[n] = 1.0f / a;
    }
}

// ---------------- embedding: h fp32 + hb bf16 (with zero k-pad) ----------------
__global__ __launch_bounds__(256) void k_h0(const int* __restrict__ x, const float* __restrict__ emb,
                                            float* __restrict__ h, unsigned short* __restrict__ hb) {
    int idx = blockIdx.x * 256 + threadIdx.x;
    if (idx < NN * HBW) {
        int n = idx / HBW, f = idx % HBW;
        if (f < FI) {
            float v = emb[x[n] * FI + f];
            h[n * FI + f] = v;
            hb[idx] = f2bf(v);
        } else {
            hb[idx] = 0;
        }
    }
}

// ---------------- weight pre-pack for k_post (all layers, once) ----------------
__global__ __launch_bounds__(256) void k_wprep(const float* __restrict__ post_w, float* __restrict__ Wpack) {
    int idx = blockIdx.x * 256 + threadIdx.x;
    if (idx >= NL * NT * WPT) return;
    int p = idx & 3;
    int o = (idx >> 2) & 15;
    int s = (idx >> 6) % 3;
    int rest = idx / 192;          // ((l*5+t)*76 + j2)
    int j2 = rest % 76;
    int lt = rest / 76;            // l*5+t
    int k = j2 * 4 + p;
    int sg = k / 76;
    int of = k - sg * 76;
    float val = 0.0f;
    if (of < 75 && o < 15)
        val = post_w[((size_t)lt * 975 + 75 + s * 300 + sg * 75 + of) * 15 + o];
    Wpack[idx] = val;
}

// ---------------- WcatT pack for MFMA preab: [NL][832 j][96 k] bf16 ----------------
__global__ __launch_bounds__(256) void k_wprep2(const float* __restrict__ pre_w,
                                                const float* __restrict__ post_w,
                                                unsigned short* __restrict__ WcatT) {
    int idx = blockIdx.x * 256 + threadIdx.x;
    if (idx >= NL * 832 * 96) return;
    int k = idx % 96;
    int j = (idx / 96) % 832;
    int l = idx / (96 * 832);
    float val = 0.0f;
    if (k < 75) {
        if (j < 375) {
            int t = j / 75, o = j % 75;
            val = pre_w[((size_t)(l * NT + t) * 225 + k) * FI + o];
        } else if (j < 750) {
            int jm = j - 375;
            int t = jm / 75, o = jm % 75;
            val = pre_w[((size_t)(l * NT + t) * 225 + 75 + k) * FI + o];
        } else if (j < 825) {
            int c = j - 750;
            int t = c / 15, o = c % 15;
            val = post_w[((size_t)(l * NT + t) * 975 + k) * 15 + o];
        }
    }
    WcatT[idx] = f2bf(val);
}

// ---------------- per-layer edge-type table (4 x 375), also zeros BN sums ----------------
__global__ __launch_bounds__(384) void k_tbl(const float* __restrict__ edge_emb, const float* __restrict__ enc_w,
                                             const float* __restrict__ enc_b, const float* __restrict__ pre_w,
                                             const float* __restrict__ pre_b, int l,
                                             float* __restrict__ tbl, float* __restrict__ bnsum) {
    __shared__ float e4[4][FI];
    int tid = threadIdx.x;
    if (tid < 150) bnsum[tid] = 0.0f;
    if (tid < 300) {
        int a = tid / FI, f = tid % FI;
        float acc = enc_b[l * FI + f];
        for (int k = 0; k < 50; k++)
            acc += edge_emb[a * 50 + k] * enc_w[(l * 50 + k) * FI + f];
        e4[a][f] = acc;
    }
    __syncthreads();
    for (int idx = tid; idx < 4 * 375; idx += 384) {
        int a = idx / 375, c = idx % 375;
        int t = c / FI, o = c % FI;
        const float* wp = pre_w + ((size_t)(l * NT + t) * 225 + 150) * FI + o;
        float acc = pre_b[(l * NT + t) * FI + o];
        for (int f = 0; f < FI; f++)
            acc += e4[a][f] * wp[f * FI];
        tbl[idx] = acc;
    }
}

// ---------------- MFMA ABH = hb @ WcatT^T  (M=30000, K=96, N=832) -> bf16 ----------------
__global__ __launch_bounds__(256) void k_preab(const unsigned short* __restrict__ hb,
                                               const unsigned short* __restrict__ WcatT,
                                               int l, __hip_bfloat16* __restrict__ ABH) {
    __shared__ __align__(16) unsigned short sA[128 * 104];
    __shared__ __align__(16) unsigned short sB[208 * 104];
    int tid = threadIdx.x;
    int m0 = blockIdx.x * 128;
    int j0 = blockIdx.y * 208;

    // stage A: 128 rows x 96 bf16 (12 x 16B chunks/row), LDS stride 104 shorts
    const uint4* hsrc = (const uint4*)hb;
    for (int c = tid; c < 128 * 12; c += 256) {
        int r = c / 12, q = c % 12;
        int n = m0 + r;
        uint4 v = make_uint4(0, 0, 0, 0);
        if (n < NN) v = hsrc[(size_t)n * 12 + q];
        *(uint4*)&sA[r * 104 + q * 8] = v;
    }
    // stage B: 208 rows (cols of ABH) x 96 k
    const uint4* wsrc = (const uint4*)(WcatT + (size_t)l * 832 * 96);
    for (int c = tid; c < 208 * 12; c += 256) {
        int r = c / 12, q = c % 12;
        *(uint4*)&sB[r * 104 + q * 8] = wsrc[(size_t)(j0 + r) * 12 + q];
    }
    __syncthreads();

    int w = tid >> 6, lane = tid & 63;
    int mw = w * 32;
    int lr = lane & 15, lq = lane >> 4;

    bf16x8 af[2][3];
    #pragma unroll
    for (int mt = 0; mt < 2; mt++)
        #pragma unroll
        for (int ks = 0; ks < 3; ks++)
            af[mt][ks] = *(const bf16x8*)&sA[(mw + mt * 16 + lr) * 104 + ks * 32 + lq * 8];

    f32x4 acc[13][2];
    #pragma unroll
    for (int nt = 0; nt < 13; nt++)
        #pragma unroll
        for (int mt = 0; mt < 2; mt++)
            acc[nt][mt] = (f32x4){0.0f, 0.0f, 0.0f, 0.0f};

    #pragma unroll
    for (int nt = 0; nt < 13; nt++) {
        #pragma unroll
        for (int ks = 0; ks < 3; ks++) {
            bf16x8 bf = *(const bf16x8*)&sB[(nt * 16 + lr) * 104 + ks * 32 + lq * 8];
            acc[nt][0] = __builtin_amdgcn_mfma_f32_16x16x32_bf16(af[0][ks], bf, acc[nt][0], 0, 0, 0);
            acc[nt][1] = __builtin_amdgcn_mfma_f32_16x16x32_bf16(af[1][ks], bf, acc[nt][1], 0, 0, 0);
        }
    }

    // epilogue: C/D mapping col=lane&15, row=(lane>>4)*4+reg  [measured m89/m91]
    #pragma unroll
    for (int nt = 0; nt < 13; nt++) {
        int col = j0 + nt * 16 + lr;
        #pragma unroll
        for (int mt = 0; mt < 2; mt++) {
            #pragma unroll
            for (int r = 0; r < 4; r++) {
                int n = m0 + mw + mt * 16 + lq * 4 + r;
                if (n < NN) ABH[(size_t)n * ABW + col] = __float2bfloat16(acc[nt][mt][r]);
            }
        }
    }
}

// ---------------- gather: per-node stats -> AGG bf16 ----------------
__global__ __launch_bounds__(256) void k_gather(const __hip_bfloat16* __restrict__ ABH,
                                                const float* __restrict__ tbl,
                                                const int* __restrict__ rowptr, const int* __restrict__ csr,
                                                unsigned short* __restrict__ AGG) {
    __shared__ float s_tbl[1500];
    int tid = threadIdx.x;
    for (int i = tid; i < 1500; i += 256) s_tbl[i] = tbl[i];
    __syncthreads();

    int w = tid >> 6, l = tid & 63;
    int n = blockIdx.x * 4 + w;
    int base = rowptr[n];
    int dg = rowptr[n + 1] - base;

    float sum[6], ss[6], mn[6], mx[6];
    #pragma unroll
    for (int j = 0; j < 6; j++) { sum[j] = 0.f; ss[j] = 0.f; mn[j] = FLT_MAX; mx[j] = -FLT_MAX; }

    const unsigned short* abu = (const unsigned short*)ABH;
    for (int k = 0; k < dg; k++) {
        int pk = csr[base + k];
        int s = pk & 0xFFFFF;
        int a = pk >> 20;
        const unsigned short* bp = abu + (size_t)s * ABW + 375;
        const float* tp = s_tbl + a * 375;
        #pragma unroll
        for (int j = 0; j < 6; j++) {
            int f = l + 64 * j;
            if (f < 375) {
                float v = bf2f(bp[f]) + tp[f];
                sum[j] += v; ss[j] += v * v;
                mn[j] = fminf(mn[j], v); mx[j] = fmaxf(mx[j], v);
            }
        }
    }

    unsigned short* out = AGG + (size_t)n * AGW;
    if (dg > 0) {
        float rc = 1.0f / (float)dg;
        const unsigned short* ap = abu + (size_t)n * ABW;
        #pragma unroll
        for (int j = 0; j < 6; j++) {
            int f = l + 64 * j;
            if (f < 375) {
                int t = f / 75, of = f - t * 75;
                int o = t * 304 + of;
                float Af = bf2f(ap[f]);
                float mean = sum[j] * rc;
                float var = ss[j] * rc - mean * mean;
                out[o]       = f2bf(Af + mean);
                out[o + 76]  = f2bf(Af + mn[j]);
                out[o + 152] = f2bf(Af + mx[j]);
                out[o + 228] = f2bf(sqrtf(fmaxf(var, 0.0f) + 1e-5f));
            }
        }
    } else {
        unsigned short z = 0;
        unsigned short sd = f2bf(0.0031622776601683794f);  // sqrt(1e-5)
        #pragma unroll
        for (int j = 0; j < 6; j++) {
            int f = l + 64 * j;
            if (f < 375) {
                int t = f / 75, of = f - t * 75;
                int o = t * 304 + of;
                out[o] = z; out[o + 76] = z; out[o + 152] = z; out[o + 228] = sd;
            }
        }
    }
    // zero the k-pads (of == 75) : 5 towers x 4 stats
    if (l < 20) out[(l >> 2) * 304 + (l & 3) * 76 + 75] = 0;
}

// ---------------- post: 5 tower-GEMMs + combine + lin + BN partials ----------------
__global__ __launch_bounds__(256) void k_post(const __hip_bfloat16* __restrict__ ABH,
                                              const unsigned int* __restrict__ AGGu,
                                              const float* __restrict__ Wpack,
                                              const float* __restrict__ amp_a, const float* __restrict__ inv_a,
                                              const float* __restrict__ post_b,
                                              const float* __restrict__ lin_w, const float* __restrict__ lin_b,
                                              int l, float* __restrict__ z, float* __restrict__ bnsum) {
    __shared__ __align__(16) float s_w[WPT];        // 58368 B (reused for lin_w)
    __shared__ float s_y[64 * 76];                  // 19456 B
    __shared__ float s_bn[152];

    int tid = threadIdx.x;
    int tx = tid & 15, ty = tid >> 4;
    int n0 = blockIdx.x * 64;
    if (tid < 152) s_bn[tid] = 0.0f;

    int nn[4]; bool nv[4];
    float am[4], iv[4];
    #pragma unroll
    for (int r = 0; r < 4; r++) {
        int n = n0 + ty + r * 16;
        nv[r] = (n < NN);
        nn[r] = nv[r] ? n : (NN - 1);
        am[r] = amp_a[nn[r]];
        iv[r] = inv_a[nn[r]];
    }
    const unsigned short* abu = (const unsigned short*)ABH;

    for (int t = 0; t < NT; t++) {
        const float4* wsrc = (const float4*)(Wpack + (size_t)(l * NT + t) * WPT);
        float4* wdst = (float4*)s_w;
        for (int i = tid; i < WPT / 4; i += 256) wdst[i] = wsrc[i];
        __syncthreads();

        float p1[4] = {}, p2[4] = {}, p3[4] = {};
        #pragma unroll 2
        for (int j2 = 0; j2 < 76; j2++) {
            const float* wb = s_w + (j2 * 3) * 64 + tx * 4;
            float4 w1 = *reinterpret_cast<const float4*>(wb);
            float4 w2 = *reinterpret_cast<const float4*>(wb + 64);
            float4 w3 = *reinterpret_cast<const float4*>(wb + 128);
            #pragma unroll
            for (int r = 0; r < 4; r++) {
                uint2 u = *reinterpret_cast<const uint2*>(AGGu + (size_t)nn[r] * 768 + t * 152 + j2 * 2);
                float f0 = __uint_as_float(u.x << 16);
                float f1 = __uint_as_float(u.x & 0xFFFF0000u);
                float f2 = __uint_as_float(u.y << 16);
                float f3 = __uint_as_float(u.y & 0xFFFF0000u);
                p1[r] += f0 * w1.x + f1 * w1.y + f2 * w1.z + f3 * w1.w;
                p2[r] += f0 * w2.x + f1 * w2.y + f2 * w2.z + f3 * w2.w;
                p3[r] += f0 * w3.x + f1 * w3.y + f2 * w3.z + f3 * w3.w;
            }
        }
        if (tx < 15) {
            float qb = post_b[(l * NT + t) * 15 + tx];
            #pragma unroll
            for (int r = 0; r < 4; r++) {
                float ht = bf2f(abu[(size_t)nn[r] * ABW + 750 + t * 15 + tx]);
                float y = ht + p1[r] + am[r] * p2[r] + iv[r] * p3[r] + qb;
                s_y[(ty + r * 16) * 76 + t * 15 + tx] = nv[r] ? y : 0.0f;
            }
        }
        __syncthreads();
    }

    for (int i = tid; i < 5625; i += 256) {
        int k = i / 75, c = i - k * 75;
        s_w[k * 80 + c] = lin_w[(size_t)l * 5625 + i];
    }
    __syncthreads();

    float acc[4][5];
    #pragma unroll
    for (int r = 0; r < 4; r++)
        #pragma unroll
        for (int u = 0; u < 5; u++) {
            int c = tx + 16 * u;
            acc[r][u] = (c < 75) ? lin_b[l * 75 + c] : 0.0f;
        }
    for (int k = 0; k < 75; k++) {
        float wv[5];
        #pragma unroll
        for (int u = 0; u < 5; u++) {
            int c = tx + 16 * u;
            wv[u] = (c < 75) ? s_w[k * 80 + c] : 0.0f;
        }
        #pragma unroll
        for (int r = 0; r < 4; r++) {
            float yv = s_y[(ty + r * 16) * 76 + k];
            #pragma unroll
            for (int u = 0; u < 5; u++) acc[r][u] += yv * wv[u];
        }
    }

    float b1a[5] = {}, b2a[5] = {};
    #pragma unroll
    for (int r = 0; r < 4; r++) {
        int n = n0 + ty + r * 16;
        #pragma unroll
        for (int u = 0; u < 5; u++) {
            int c = tx + 16 * u;
            if (c < 75 && nv[r]) {
                z[(size_t)n * 75 + c] = acc[r][u];
                b1a[u] += acc[r][u];
                b2a[u] += acc[r][u] * acc[r][u];
            }
        }
    }
    #pragma unroll
    for (int u = 0; u < 5; u++) {
        b1a[u] += __shfl_xor(b1a[u], 16); b1a[u] += __shfl_xor(b1a[u], 32);
        b2a[u] += __shfl_xor(b2a[u], 16); b2a[u] += __shfl_xor(b2a[u], 32);
    }
    if ((tid & 63) < 16) {
        #pragma unroll
        for (int u = 0; u < 5; u++) {
            int c = tx + 16 * u;
            if (c < 75) {
                atomicAdd(&s_bn[c], b1a[u]);
                atomicAdd(&s_bn[76 + c], b2a[u]);
            }
        }
    }
    __syncthreads();
    if (tid < 75) {
        atomicAdd(&bnsum[tid], s_bn[tid]);
        atomicAdd(&bnsum[75 + tid], s_bn[76 + tid]);
    }
}

// ---------------- BN + ReLU (writes h fp32 + hb bf16) ----------------
__global__ __launch_bounds__(256) void k_bn(const float* __restrict__ z, const float* __restrict__ bnsum,
                                            const float* __restrict__ bn_g, const float* __restrict__ bn_b,
                                            int l, float* __restrict__ h, unsigned short* __restrict__ hb) {
    int idx = blockIdx.x * 256 + threadIdx.x;
    if (idx < NN * 75) {
        int n = idx / 75, c = idx % 75;
        float mu = bnsum[c] * (1.0f / NN);
        float msq = bnsum[75 + c] * (1.0f / NN);
        float var = msq - mu * mu;
        float v = (z[idx] - mu) * rsqrtf(var + 1e-5f) * bn_g[l * 75 + c] + bn_b[l * 75 + c];
        v = fmaxf(v, 0.0f);
        h[idx] = v;
        hb[n * HBW + c] = f2bf(v);
    }
}

// ---------------- pooling + MLP ----------------
__global__ __launch_bounds__(256) void k_pool(const float* __restrict__ h, const int* __restrict__ batch,
                                              float* __restrict__ hg) {
    int idx = blockIdx.x * 256 + threadIdx.x;
    if (idx < NN * 75) {
        int n = idx / 75, f = idx % 75;
        atomicAdd(&hg[batch[n] * 75 + f], h[idx]);
    }
}

__global__ __launch_bounds__(64) void k_mlp(const float* __restrict__ hg,
                                            const float* __restrict__ w1, const float* __restrict__ b1,
                                            const float* __restrict__ w2, const float* __restrict__ b2,
                                            const float* __restrict__ w3, const float* __restrict__ b3,
                                            float* __restrict__ out) {
    __shared__ float zin[75], z1[50], z2[25];
    int g = blockIdx.x, tid = threadIdx.x;
    for (int k = tid; k < 75; k += 64) zin[k] = hg[g * 75 + k];
    __syncthreads();
    if (tid < 50) {
        float acc = b1[tid];
        for (int k = 0; k < 75; k++) acc += zin[k] * w1[k * 50 + tid];
        z1[tid] = fmaxf(acc, 0.0f);
    }
    __syncthreads();
    if (tid < 25) {
        float acc = b2[tid];
        for (int k = 0; k < 50; k++) acc += z1[k] * w2[k * 25 + tid];
        z2[tid] = fmaxf(acc, 0.0f);
    }
    __syncthreads();
    if (tid == 0) {
        float acc = b3[0];
        for (int k = 0; k < 25; k++) acc += z2[k] * w3[k];
        out[g] = acc;
    }
}

extern "C" void kernel_launch(void* const* d_in, const int* in_sizes, int n_in,
                              void* d_out, int out_size, void* d_ws, size_t ws_size,
                              hipStream_t stream) {
    const int* x        = (const int*)d_in[0];
    const int* ei       = (const int*)d_in[1];
    const int* eattr    = (const int*)d_in[2];
    const int* batch    = (const int*)d_in[3];
    const float* node_emb = (const float*)d_in[4];
    const float* edge_emb = (const float*)d_in[5];
    const float* enc_w  = (const float*)d_in[6];
    const float* enc_b  = (const float*)d_in[7];
    const float* pre_w  = (const float*)d_in[8];
    const float* pre_b  = (const float*)d_in[9];
    const float* post_w = (const float*)d_in[10];
    const float* post_b = (const float*)d_in[11];
    const float* lin_w  = (const float*)d_in[12];
    const float* lin_b  = (const float*)d_in[13];
    const float* bn_g   = (const float*)d_in[14];
    const float* bn_b   = (const float*)d_in[15];
    const float* w1     = (const float*)d_in[16];
    const float* b1     = (const float*)d_in[17];
    const float* w2     = (const float*)d_in[18];
    const float* b2     = (const float*)d_in[19];
    const float* w3     = (const float*)d_in[20];
    const float* b3     = (const float*)d_in[21];

    char* p = (char*)d_ws;
    auto carve = [&](size_t bytes) -> char* {
        char* r = p;
        p += ((bytes + 255) & ~(size_t)255);
        return r;
    };
    __hip_bfloat16* ABH = (__hip_bfloat16*)carve((size_t)NN * ABW * 2);
    unsigned short* AGG = (unsigned short*)carve((size_t)NN * AGW * 2);
    float* h     = (float*)carve((size_t)NN * 75 * 4);
    float* z     = (float*)carve((size_t)NN * 75 * 4);
    unsigned short* hb = (unsigned short*)carve((size_t)NN * HBW * 2);
    unsigned short* WcatT = (unsigned short*)carve((size_t)NL * 832 * 96 * 2);
    float* Wpack = (float*)carve((size_t)NL * NT * WPT * 4);
    float* tbl   = (float*)carve(1500 * 4);
    int* deg     = (int*)carve(NN * 4);
    int* rowptr  = (int*)carve((NN + 1) * 4);
    int* fill    = (int*)carve(NN * 4);
    int* csr     = (int*)carve(NE * 4);
    float* bnsum = (float*)carve(150 * 4);
    float* amp_a = (float*)carve(NN * 4);
    float* inv_a = (float*)carve(NN * 4);
    float* hg    = (float*)carve((size_t)NG * 75 * 4);

    hipMemsetAsync(deg, 0, NN * 4, stream);
    hipMemsetAsync(fill, 0, NN * 4, stream);
    hipMemsetAsync(hg, 0, (size_t)NG * 75 * 4, stream);

    k_deg<<<(NE + 255) / 256, 256, 0, stream>>>(ei + NE, deg);
    k_scan<<<1, 1024, 0, stream>>>(deg, rowptr);
    k_scatter<<<(NE + 255) / 256, 256, 0, stream>>>(ei, ei + NE, eattr, rowptr, fill, csr);
    k_amp<<<(NN + 255) / 256, 256, 0, stream>>>(rowptr, amp_a, inv_a);
    k_h0<<<(NN * HBW + 255) / 256, 256, 0, stream>>>(x, node_emb, h, hb);
    k_wprep<<<(NL * NT * WPT + 255) / 256, 256, 0, stream>>>(post_w, Wpack);
    k_wprep2<<<(NL * 832 * 96 + 255) / 256, 256, 0, stream>>>(pre_w, post_w, WcatT);

    for (int l = 0; l < NL; l++) {
        k_tbl<<<1, 384, 0, stream>>>(edge_emb, enc_w, enc_b, pre_w, pre_b, l, tbl, bnsum);
        k_preab<<<dim3((NN + 127) / 128, 4), 256, 0, stream>>>(hb, WcatT, l, ABH);
        k_gather<<<NN / 4, 256, 0, stream>>>(ABH, tbl, rowptr, csr, AGG);
        k_post<<<(NN + 63) / 64, 256, 0, stream>>>(ABH, (const unsigned int*)AGG, Wpack, amp_a, inv_a,
                                                   post_b, lin_w, lin_b, l, z, bnsum);
        k_bn<<<(NN * 75 + 255) / 256, 256, 0, stream>>>(z, bnsum, bn_g, bn_b, l, h, hb);
    }

    k_pool<<<(NN * 75 + 255) / 256, 256, 0, stream>>>(h, batch, hg);
    k_mlp<<<NG, 64, 0, stream>>>(hg, w1, b1, w2, b2, w3, b3, (float*)d_out);
}

// Round 5
// 589.708 us; speedup vs baseline: 10.4969x; 1.7678x over previous
//
#include <hip/hip_runtime.h>
#include <hip/hip_bf16.h>
#include <float.h>
#include <math.h>

#define NN 30000
#define NE 70000
#define NG 1024
#define NT 5
#define FI 75
#define NL 4

// AVG_DEG_LOG = (100*ln2 + 400*ln3 + 300*ln4 + 50*ln5)/850
#define AMP_DENOM 1.1824939264481302f

// ABH: [NN][832] bf16 : cols 0..374 = A (h@Wdst), 375..749 = B (h@Wsrc),
//                        750..824 = hterm (h@post_w rows 0..74), 825..831 pad
#define ABW 832
// AGG: [NN][1600] bf16 : per tower t (5): 320 = 4 stats x 76 (75 + pad) + 16 k-pad, pads zero
#define AGW 1600
// hb: [NN][96] bf16, cols 75..95 zero.  WcatT: [NL][832][96] bf16, k rows 75..95 zero.
#define HBW 96
// Wpost2: [NL][NT][3 s][16 col][SBH k] bf16 (k<304 real = stat*76+of, rest zero; col 15 zero)
#define SBH 328

typedef __attribute__((ext_vector_type(8))) short bf16x8;
typedef __attribute__((ext_vector_type(4))) float f32x4;

__device__ __forceinline__ float bf2f(unsigned short u) {
    return __uint_as_float(((unsigned int)u) << 16);
}
__device__ __forceinline__ unsigned short f2bf(float f) {
    __hip_bfloat16 h = __float2bfloat16(f);
    return *reinterpret_cast<unsigned short*>(&h);
}

// ---------------- CSR build ----------------
__global__ __launch_bounds__(256) void k_deg(const int* __restrict__ dst, int* __restrict__ deg) {
    int e = blockIdx.x * 256 + threadIdx.x;
    if (e < NE) atomicAdd(&deg[dst[e]], 1);
}

__global__ __launch_bounds__(1024) void k_scan(const int* __restrict__ deg, int* __restrict__ rowptr) {
    __shared__ int wsum[16];
    __shared__ int s_carry;
    int tid = threadIdx.x;
    int lane = tid & 63, wv = tid >> 6;
    if (tid == 0) s_carry = 0;
    __syncthreads();
    for (int base = 0; base < NN; base += 1024) {
        int i = base + tid;
        int v = (i < NN) ? deg[i] : 0;
        int x = v;
        #pragma unroll
        for (int off = 1; off < 64; off <<= 1) {
            int t = __shfl_up(x, off);
            if (lane >= off) x += t;
        }
        if (lane == 63) wsum[wv] = x;
        __syncthreads();
        if (tid < 16) {
            int y = wsum[tid];
            #pragma unroll
            for (int off = 1; off < 16; off <<= 1) {
                int t = __shfl_up(y, off);
                if (tid >= off) y += t;
            }
            wsum[tid] = y;
        }
        __syncthreads();
        int wbase = ((wv > 0) ? wsum[wv - 1] : 0) + s_carry;
        if (i < NN) rowptr[i] = wbase + x - v;
        int tot = wsum[15];
        __syncthreads();
        if (tid == 0) s_carry += tot;
    }
    __syncthreads();
    if (tid == 0) rowptr[NN] = s_carry;
}

__global__ __launch_bounds__(256) void k_scatter(const int* __restrict__ src, const int* __restrict__ dst,
                                                 const int* __restrict__ attr, const int* __restrict__ rowptr,
                                                 int* __restrict__ fill, int* __restrict__ csr) {
    int e = blockIdx.x * 256 + threadIdx.x;
    if (e < NE) {
        int d = dst[e];
        int pos = rowptr[d] + atomicAdd(&fill[d], 1);
        csr[pos] = src[e] | (attr[e] << 20);
    }
}

// amp/inv per node (degree-only, layer-invariant)
__global__ __launch_bounds__(256) void k_amp(const int* __restrict__ rowptr,
                                             float* __restrict__ amp, float* __restrict__ inv) {
    int n = blockIdx.x * 256 + threadIdx.x;
    if (n < NN) {
        int dg = rowptr[n + 1] - rowptr[n];
        float cnt = fmaxf((float)dg, 1.0f);
        float a = logf(cnt + 1.0f) * (1.0f / AMP_DENOM);
        amp[n] = a;
        inv[n] = 1.0f / a;
    }
}

// ---------------- embedding: h fp32 + hb bf16 (with zero k-pad) ----------------
__global__ __launch_bounds__(256) void k_h0(const int* __restrict__ x, const float* __restrict__ emb,
                                            float* __restrict__ h, unsigned short* __restrict__ hb) {
    int idx = blockIdx.x * 256 + threadIdx.x;
    if (idx < NN * HBW) {
        int n = idx / HBW, f = idx % HBW;
        if (f < FI) {
            float v = emb[x[n] * FI + f];
            h[n * FI + f] = v;
            hb[idx] = f2bf(v);
        } else {
            hb[idx] = 0;
        }
    }
}

// ---------------- Wpost2 pack (all layers, once): [NL][NT][3][16][SBH] bf16 ----------------
__global__ __launch_bounds__(256) void k_wprep3(const float* __restrict__ post_w,
                                                unsigned short* __restrict__ Wpost2) {
    int idx = blockIdx.x * 256 + threadIdx.x;
    if (idx >= NL * NT * 3 * 16 * SBH) return;
    int kk = idx % SBH;
    int col = (idx / SBH) & 15;
    int s = (idx / (SBH * 16)) % 3;
    int t = (idx / (SBH * 16 * 3)) % NT;
    int l = idx / (SBH * 16 * 3 * NT);
    float val = 0.0f;
    if (kk < 304 && col < 15) {
        int stat = kk / 76, of = kk - stat * 76;
        if (of < 75)
            val = post_w[((size_t)(l * NT + t) * 975 + 75 + s * 300 + stat * 75 + of) * 15 + col];
    }
    Wpost2[idx] = f2bf(val);
}

// ---------------- WcatT pack for MFMA preab: [NL][832 j][96 k] bf16 ----------------
__global__ __launch_bounds__(256) void k_wprep2(const float* __restrict__ pre_w,
                                                const float* __restrict__ post_w,
                                                unsigned short* __restrict__ WcatT) {
    int idx = blockIdx.x * 256 + threadIdx.x;
    if (idx >= NL * 832 * 96) return;
    int k = idx % 96;
    int j = (idx / 96) % 832;
    int l = idx / (96 * 832);
    float val = 0.0f;
    if (k < 75) {
        if (j < 375) {
            int t = j / 75, o = j % 75;
            val = pre_w[((size_t)(l * NT + t) * 225 + k) * FI + o];
        } else if (j < 750) {
            int jm = j - 375;
            int t = jm / 75, o = jm % 75;
            val = pre_w[((size_t)(l * NT + t) * 225 + 75 + k) * FI + o];
        } else if (j < 825) {
            int c = j - 750;
            int t = c / 15, o = c % 15;
            val = post_w[((size_t)(l * NT + t) * 975 + k) * 15 + o];
        }
    }
    WcatT[idx] = f2bf(val);
}

// ---------------- per-layer edge-type table (4 x 375), also zeros BN sums ----------------
__global__ __launch_bounds__(384) void k_tbl(const float* __restrict__ edge_emb, const float* __restrict__ enc_w,
                                             const float* __restrict__ enc_b, const float* __restrict__ pre_w,
                                             const float* __restrict__ pre_b, int l,
                                             float* __restrict__ tbl, float* __restrict__ bnsum) {
    __shared__ float e4[4][FI];
    int tid = threadIdx.x;
    if (tid < 150) bnsum[tid] = 0.0f;
    if (tid < 300) {
        int a = tid / FI, f = tid % FI;
        float acc = enc_b[l * FI + f];
        for (int k = 0; k < 50; k++)
            acc += edge_emb[a * 50 + k] * enc_w[(l * 50 + k) * FI + f];
        e4[a][f] = acc;
    }
    __syncthreads();
    for (int idx = tid; idx < 4 * 375; idx += 384) {
        int a = idx / 375, c = idx % 375;
        int t = c / FI, o = c % FI;
        const float* wp = pre_w + ((size_t)(l * NT + t) * 225 + 150) * FI + o;
        float acc = pre_b[(l * NT + t) * FI + o];
        for (int f = 0; f < FI; f++)
            acc += e4[a][f] * wp[f * FI];
        tbl[idx] = acc;
    }
}

// ---------------- MFMA ABH = hb @ WcatT^T  (M=30000, K=96, N=832) -> bf16 ----------------
__global__ __launch_bounds__(256) void k_preab(const unsigned short* __restrict__ hb,
                                               const unsigned short* __restrict__ WcatT,
                                               int l, __hip_bfloat16* __restrict__ ABH) {
    __shared__ __align__(16) unsigned short sA[128 * 104];
    __shared__ __align__(16) unsigned short sB[208 * 104];
    int tid = threadIdx.x;
    int m0 = blockIdx.x * 128;
    int j0 = blockIdx.y * 208;

    const uint4* hsrc = (const uint4*)hb;
    for (int c = tid; c < 128 * 12; c += 256) {
        int r = c / 12, q = c % 12;
        int n = m0 + r;
        uint4 v = make_uint4(0, 0, 0, 0);
        if (n < NN) v = hsrc[(size_t)n * 12 + q];
        *(uint4*)&sA[r * 104 + q * 8] = v;
    }
    const uint4* wsrc = (const uint4*)(WcatT + (size_t)l * 832 * 96);
    for (int c = tid; c < 208 * 12; c += 256) {
        int r = c / 12, q = c % 12;
        *(uint4*)&sB[r * 104 + q * 8] = wsrc[(size_t)(j0 + r) * 12 + q];
    }
    __syncthreads();

    int w = tid >> 6, lane = tid & 63;
    int mw = w * 32;
    int lr = lane & 15, lq = lane >> 4;

    bf16x8 af[2][3];
    #pragma unroll
    for (int mt = 0; mt < 2; mt++)
        #pragma unroll
        for (int ks = 0; ks < 3; ks++)
            af[mt][ks] = *(const bf16x8*)&sA[(mw + mt * 16 + lr) * 104 + ks * 32 + lq * 8];

    f32x4 acc[13][2];
    #pragma unroll
    for (int nt = 0; nt < 13; nt++)
        #pragma unroll
        for (int mt = 0; mt < 2; mt++)
            acc[nt][mt] = (f32x4){0.0f, 0.0f, 0.0f, 0.0f};

    #pragma unroll
    for (int nt = 0; nt < 13; nt++) {
        #pragma unroll
        for (int ks = 0; ks < 3; ks++) {
            bf16x8 bf = *(const bf16x8*)&sB[(nt * 16 + lr) * 104 + ks * 32 + lq * 8];
            acc[nt][0] = __builtin_amdgcn_mfma_f32_16x16x32_bf16(af[0][ks], bf, acc[nt][0], 0, 0, 0);
            acc[nt][1] = __builtin_amdgcn_mfma_f32_16x16x32_bf16(af[1][ks], bf, acc[nt][1], 0, 0, 0);
        }
    }

    // epilogue: C/D mapping col=lane&15, row=(lane>>4)*4+reg  [measured m89/m91]
    #pragma unroll
    for (int nt = 0; nt < 13; nt++) {
        int col = j0 + nt * 16 + lr;
        #pragma unroll
        for (int mt = 0; mt < 2; mt++) {
            #pragma unroll
            for (int r = 0; r < 4; r++) {
                int n = m0 + mw + mt * 16 + lq * 4 + r;
                if (n < NN) ABH[(size_t)n * ABW + col] = __float2bfloat16(acc[nt][mt][r]);
            }
        }
    }
}

// ---------------- gather: per-node stats -> AGG bf16 (stride 1600, padded) ----------------
__global__ __launch_bounds__(256) void k_gather(const __hip_bfloat16* __restrict__ ABH,
                                                const float* __restrict__ tbl,
                                                const int* __restrict__ rowptr, const int* __restrict__ csr,
                                                unsigned short* __restrict__ AGG) {
    __shared__ float s_tbl[1500];
    int tid = threadIdx.x;
    for (int i = tid; i < 1500; i += 256) s_tbl[i] = tbl[i];
    __syncthreads();

    int w = tid >> 6, l = tid & 63;
    int n = blockIdx.x * 4 + w;
    int base = rowptr[n];
    int dg = rowptr[n + 1] - base;

    float sum[6], ss[6], mn[6], mx[6];
    #pragma unroll
    for (int j = 0; j < 6; j++) { sum[j] = 0.f; ss[j] = 0.f; mn[j] = FLT_MAX; mx[j] = -FLT_MAX; }

    const unsigned short* abu = (const unsigned short*)ABH;
    for (int k = 0; k < dg; k++) {
        int pk = csr[base + k];
        int s = pk & 0xFFFFF;
        int a = pk >> 20;
        const unsigned short* bp = abu + (size_t)s * ABW + 375;
        const float* tp = s_tbl + a * 375;
        #pragma unroll
        for (int j = 0; j < 6; j++) {
            int f = l + 64 * j;
            if (f < 375) {
                float v = bf2f(bp[f]) + tp[f];
                sum[j] += v; ss[j] += v * v;
                mn[j] = fminf(mn[j], v); mx[j] = fmaxf(mx[j], v);
            }
        }
    }

    unsigned short* out = AGG + (size_t)n * AGW;
    if (dg > 0) {
        float rc = 1.0f / (float)dg;
        const unsigned short* ap = abu + (size_t)n * ABW;
        #pragma unroll
        for (int j = 0; j < 6; j++) {
            int f = l + 64 * j;
            if (f < 375) {
                int t = f / 75, of = f - t * 75;
                int o = t * 320 + of;
                float Af = bf2f(ap[f]);
                float mean = sum[j] * rc;
                float var = ss[j] * rc - mean * mean;
                out[o]       = f2bf(Af + mean);
                out[o + 76]  = f2bf(Af + mn[j]);
                out[o + 152] = f2bf(Af + mx[j]);
                out[o + 228] = f2bf(sqrtf(fmaxf(var, 0.0f) + 1e-5f));
            }
        }
    } else {
        unsigned short zz = 0;
        unsigned short sd = f2bf(0.0031622776601683794f);  // sqrt(1e-5)
        #pragma unroll
        for (int j = 0; j < 6; j++) {
            int f = l + 64 * j;
            if (f < 375) {
                int t = f / 75, of = f - t * 75;
                int o = t * 320 + of;
                out[o] = zz; out[o + 76] = zz; out[o + 152] = zz; out[o + 228] = sd;
            }
        }
    }
    // zero pads: per tower k in [304,320), and stat pads of==75 (k = stat*76+75)
    for (int i = l; i < 80; i += 64) out[(i >> 4) * 320 + 304 + (i & 15)] = 0;
    if (l < 20) out[(l >> 2) * 320 + (l & 3) * 76 + 75] = 0;
}

// ---------------- post: MFMA tower-GEMMs (3 streams) + combine + lin + BN ----------------
__global__ __launch_bounds__(256) void k_post(const __hip_bfloat16* __restrict__ ABH,
                                              const unsigned short* __restrict__ AGG,
                                              const unsigned short* __restrict__ Wpost2,
                                              const float* __restrict__ amp_a, const float* __restrict__ inv_a,
                                              const float* __restrict__ post_b,
                                              const float* __restrict__ lin_w, const float* __restrict__ lin_b,
                                              int l, float* __restrict__ z, float* __restrict__ bnsum) {
    __shared__ __align__(16) float s_y[128 * 84];                 // 43008 B
    __shared__ __align__(16) unsigned short sB[3 * 16 * SBH];     // 31488 B (reused as f32 lin_w)
    __shared__ float s_bn[152];

    int tid = threadIdx.x;
    int n0 = blockIdx.x * 128;
    int w = tid >> 6, lane = tid & 63;
    int lr = lane & 15, lq = lane >> 4;
    int mw = w * 32;
    if (tid < 152) s_bn[tid] = 0.0f;

    // rows this lane's acc covers: mw + mt*16 + lq*4 + r
    float am[2][4], iv[2][4];
    int rown[2][4];
    #pragma unroll
    for (int mt = 0; mt < 2; mt++)
        #pragma unroll
        for (int r = 0; r < 4; r++) {
            int n = n0 + mw + mt * 16 + lq * 4 + r;
            int nc = (n < NN) ? n : (NN - 1);
            rown[mt][r] = nc;
            am[mt][r] = amp_a[nc];
            iv[mt][r] = inv_a[nc];
        }
    // rows this lane's A-fragment feeds: mw + mt*16 + lr
    int arow[2];
    #pragma unroll
    for (int mt = 0; mt < 2; mt++) {
        int n = n0 + mw + mt * 16 + lr;
        arow[mt] = (n < NN) ? n : (NN - 1);
    }

    const unsigned short* abu = (const unsigned short*)ABH;
    const unsigned short* wbase = Wpost2 + (size_t)l * NT * 3 * 16 * SBH;

    for (int t = 0; t < NT; t++) {
        __syncthreads();
        const uint4* gsrc = (const uint4*)(wbase + (size_t)t * 3 * 16 * SBH);
        uint4* gdst = (uint4*)sB;
        for (int i = tid; i < 3 * 16 * SBH / 8; i += 256) gdst[i] = gsrc[i];
        __syncthreads();

        f32x4 acc[2][3];
        #pragma unroll
        for (int mt = 0; mt < 2; mt++)
            #pragma unroll
            for (int s = 0; s < 3; s++)
                acc[mt][s] = (f32x4){0.0f, 0.0f, 0.0f, 0.0f};

        const unsigned short* a0p = AGG + (size_t)arow[0] * AGW + t * 320;
        const unsigned short* a1p = AGG + (size_t)arow[1] * AGW + t * 320;
        #pragma unroll
        for (int ks = 0; ks < 10; ks++) {
            int off = ks * 32 + lq * 8;
            bf16x8 b0 = *(const bf16x8*)&sB[0 * 16 * SBH + lr * SBH + off];
            bf16x8 b1 = *(const bf16x8*)&sB[1 * 16 * SBH + lr * SBH + off];
            bf16x8 b2 = *(const bf16x8*)&sB[2 * 16 * SBH + lr * SBH + off];
            bf16x8 a0 = *(const bf16x8*)&a0p[off];
            bf16x8 a1 = *(const bf16x8*)&a1p[off];
            acc[0][0] = __builtin_amdgcn_mfma_f32_16x16x32_bf16(a0, b0, acc[0][0], 0, 0, 0);
            acc[0][1] = __builtin_amdgcn_mfma_f32_16x16x32_bf16(a0, b1, acc[0][1], 0, 0, 0);
            acc[0][2] = __builtin_amdgcn_mfma_f32_16x16x32_bf16(a0, b2, acc[0][2], 0, 0, 0);
            acc[1][0] = __builtin_amdgcn_mfma_f32_16x16x32_bf16(a1, b0, acc[1][0], 0, 0, 0);
            acc[1][1] = __builtin_amdgcn_mfma_f32_16x16x32_bf16(a1, b1, acc[1][1], 0, 0, 0);
            acc[1][2] = __builtin_amdgcn_mfma_f32_16x16x32_bf16(a1, b2, acc[1][2], 0, 0, 0);
        }

        // combine: y = P1 + amp*P2 + inv*P3 + hterm + bias  (col=lr, row=lq*4+r)
        if (lr < 15) {
            float qb = post_b[(l * NT + t) * 15 + lr];
            #pragma unroll
            for (int mt = 0; mt < 2; mt++)
                #pragma unroll
                for (int r = 0; r < 4; r++) {
                    float ht = bf2f(abu[(size_t)rown[mt][r] * ABW + 750 + t * 15 + lr]);
                    float y = acc[mt][0][r] + am[mt][r] * acc[mt][1][r] + iv[mt][r] * acc[mt][2][r] + ht + qb;
                    s_y[(mw + mt * 16 + lq * 4 + r) * 84 + t * 15 + lr] = y;
                }
        }
    }
    __syncthreads();

    // lin: stage lin_w as f32 into sB region
    float* s_lw = (float*)sB;
    for (int i = tid; i < 5625; i += 256) {
        int k = i / 75, c = i - k * 75;
        s_lw[k * 80 + c] = lin_w[(size_t)l * 5625 + i];
    }
    __syncthreads();

    int tx = tid & 15, ty = tid >> 4;
    float acc2[8][5];
    #pragma unroll
    for (int r = 0; r < 8; r++)
        #pragma unroll
        for (int u = 0; u < 5; u++) {
            int c = tx + 16 * u;
            acc2[r][u] = (c < 75) ? lin_b[l * 75 + c] : 0.0f;
        }
    for (int k = 0; k < 75; k++) {
        float wv[5];
        #pragma unroll
        for (int u = 0; u < 5; u++) {
            int c = tx + 16 * u;
            wv[u] = (c < 75) ? s_lw[k * 80 + c] : 0.0f;
        }
        #pragma unroll
        for (int r = 0; r < 8; r++) {
            float yv = s_y[(ty + r * 16) * 84 + k];
            #pragma unroll
            for (int u = 0; u < 5; u++) acc2[r][u] += yv * wv[u];
        }
    }

    float b1a[5] = {}, b2a[5] = {};
    #pragma unroll
    for (int r = 0; r < 8; r++) {
        int n = n0 + ty + r * 16;
        bool nv = (n < NN);
        #pragma unroll
        for (int u = 0; u < 5; u++) {
            int c = tx + 16 * u;
            if (c < 75 && nv) {
                z[(size_t)n * 75 + c] = acc2[r][u];
                b1a[u] += acc2[r][u];
                b2a[u] += acc2[r][u] * acc2[r][u];
            }
        }
    }
    #pragma unroll
    for (int u = 0; u < 5; u++) {
        b1a[u] += __shfl_xor(b1a[u], 16); b1a[u] += __shfl_xor(b1a[u], 32);
        b2a[u] += __shfl_xor(b2a[u], 16); b2a[u] += __shfl_xor(b2a[u], 32);
    }
    if ((tid & 63) < 16) {
        #pragma unroll
        for (int u = 0; u < 5; u++) {
            int c = tx + 16 * u;
            if (c < 75) {
                atomicAdd(&s_bn[c], b1a[u]);
                atomicAdd(&s_bn[76 + c], b2a[u]);
            }
        }
    }
    __syncthreads();
    if (tid < 75) {
        atomicAdd(&bnsum[tid], s_bn[tid]);
        atomicAdd(&bnsum[75 + tid], s_bn[76 + tid]);
    }
}

// ---------------- BN + ReLU (writes h fp32 + hb bf16) ----------------
__global__ __launch_bounds__(256) void k_bn(const float* __restrict__ z, const float* __restrict__ bnsum,
                                            const float* __restrict__ bn_g, const float* __restrict__ bn_b,
                                            int l, float* __restrict__ h, unsigned short* __restrict__ hb) {
    int idx = blockIdx.x * 256 + threadIdx.x;
    if (idx < NN * 75) {
        int n = idx / 75, c = idx % 75;
        float mu = bnsum[c] * (1.0f / NN);
        float msq = bnsum[75 + c] * (1.0f / NN);
        float var = msq - mu * mu;
        float v = (z[idx] - mu) * rsqrtf(var + 1e-5f) * bn_g[l * 75 + c] + bn_b[l * 75 + c];
        v = fmaxf(v, 0.0f);
        h[idx] = v;
        hb[n * HBW + c] = f2bf(v);
    }
}

// ---------------- pooling + MLP ----------------
__global__ __launch_bounds__(256) void k_pool(const float* __restrict__ h, const int* __restrict__ batch,
                                              float* __restrict__ hg) {
    int idx = blockIdx.x * 256 + threadIdx.x;
    if (idx < NN * 75) {
        int n = idx / 75, f = idx % 75;
        atomicAdd(&hg[batch[n] * 75 + f], h[idx]);
    }
}

__global__ __launch_bounds__(64) void k_mlp(const float* __restrict__ hg,
                                            const float* __restrict__ w1, const float* __restrict__ b1,
                                            const float* __restrict__ w2, const float* __restrict__ b2,
                                            const float* __restrict__ w3, const float* __restrict__ b3,
                                            float* __restrict__ out) {
    __shared__ float zin[75], z1[50], z2[25];
    int g = blockIdx.x, tid = threadIdx.x;
    for (int k = tid; k < 75; k += 64) zin[k] = hg[g * 75 + k];
    __syncthreads();
    if (tid < 50) {
        float acc = b1[tid];
        for (int k = 0; k < 75; k++) acc += zin[k] * w1[k * 50 + tid];
        z1[tid] = fmaxf(acc, 0.0f);
    }
    __syncthreads();
    if (tid < 25) {
        float acc = b2[tid];
        for (int k = 0; k < 50; k++) acc += z1[k] * w2[k * 25 + tid];
        z2[tid] = fmaxf(acc, 0.0f);
    }
    __syncthreads();
    if (tid == 0) {
        float acc = b3[0];
        for (int k = 0; k < 25; k++) acc += z2[k] * w3[k];
        out[g] = acc;
    }
}

extern "C" void kernel_launch(void* const* d_in, const int* in_sizes, int n_in,
                              void* d_out, int out_size, void* d_ws, size_t ws_size,
                              hipStream_t stream) {
    const int* x        = (const int*)d_in[0];
    const int* ei       = (const int*)d_in[1];
    const int* eattr    = (const int*)d_in[2];
    const int* batch    = (const int*)d_in[3];
    const float* node_emb = (const float*)d_in[4];
    const float* edge_emb = (const float*)d_in[5];
    const float* enc_w  = (const float*)d_in[6];
    const float* enc_b  = (const float*)d_in[7];
    const float* pre_w  = (const float*)d_in[8];
    const float* pre_b  = (const float*)d_in[9];
    const float* post_w = (const float*)d_in[10];
    const float* post_b = (const float*)d_in[11];
    const float* lin_w  = (const float*)d_in[12];
    const float* lin_b  = (const float*)d_in[13];
    const float* bn_g   = (const float*)d_in[14];
    const float* bn_b   = (const float*)d_in[15];
    const float* w1     = (const float*)d_in[16];
    const float* b1     = (const float*)d_in[17];
    const float* w2     = (const float*)d_in[18];
    const float* b2     = (const float*)d_in[19];
    const float* w3     = (const float*)d_in[20];
    const float* b3     = (const float*)d_in[21];

    char* p = (char*)d_ws;
    auto carve = [&](size_t bytes) -> char* {
        char* r = p;
        p += ((bytes + 255) & ~(size_t)255);
        return r;
    };
    __hip_bfloat16* ABH = (__hip_bfloat16*)carve((size_t)NN * ABW * 2);
    unsigned short* AGG = (unsigned short*)carve((size_t)NN * AGW * 2);
    float* h     = (float*)carve((size_t)NN * 75 * 4);
    float* z     = (float*)carve((size_t)NN * 75 * 4);
    unsigned short* hb = (unsigned short*)carve((size_t)NN * HBW * 2);
    unsigned short* WcatT = (unsigned short*)carve((size_t)NL * 832 * 96 * 2);
    unsigned short* Wpost2 = (unsigned short*)carve((size_t)NL * NT * 3 * 16 * SBH * 2);
    float* tbl   = (float*)carve(1500 * 4);
    int* deg     = (int*)carve(NN * 4);
    int* rowptr  = (int*)carve((NN + 1) * 4);
    int* fill    = (int*)carve(NN * 4);
    int* csr     = (int*)carve(NE * 4);
    float* bnsum = (float*)carve(150 * 4);
    float* amp_a = (float*)carve(NN * 4);
    float* inv_a = (float*)carve(NN * 4);
    float* hg    = (float*)carve((size_t)NG * 75 * 4);

    hipMemsetAsync(deg, 0, NN * 4, stream);
    hipMemsetAsync(fill, 0, NN * 4, stream);
    hipMemsetAsync(hg, 0, (size_t)NG * 75 * 4, stream);

    k_deg<<<(NE + 255) / 256, 256, 0, stream>>>(ei + NE, deg);
    k_scan<<<1, 1024, 0, stream>>>(deg, rowptr);
    k_scatter<<<(NE + 255) / 256, 256, 0, stream>>>(ei, ei + NE, eattr, rowptr, fill, csr);
    k_amp<<<(NN + 255) / 256, 256, 0, stream>>>(rowptr, amp_a, inv_a);
    k_h0<<<(NN * HBW + 255) / 256, 256, 0, stream>>>(x, node_emb, h, hb);
    k_wprep3<<<(NL * NT * 3 * 16 * SBH + 255) / 256, 256, 0, stream>>>(post_w, Wpost2);
    k_wprep2<<<(NL * 832 * 96 + 255) / 256, 256, 0, stream>>>(pre_w, post_w, WcatT);

    for (int l = 0; l < NL; l++) {
        k_tbl<<<1, 384, 0, stream>>>(edge_emb, enc_w, enc_b, pre_w, pre_b, l, tbl, bnsum);
        k_preab<<<dim3((NN + 127) / 128, 4), 256, 0, stream>>>(hb, WcatT, l, ABH);
        k_gather<<<NN / 4, 256, 0, stream>>>(ABH, tbl, rowptr, csr, AGG);
        k_post<<<(NN + 127) / 128, 256, 0, stream>>>(ABH, AGG, Wpost2, amp_a, inv_a,
                                                     post_b, lin_w, lin_b, l, z, bnsum);
        k_bn<<<(NN * 75 + 255) / 256, 256, 0, stream>>>(z, bnsum, bn_g, bn_b, l, h, hb);
    }

    k_pool<<<(NN * 75 + 255) / 256, 256, 0, stream>>>(h, batch, hg);
    k_mlp<<<NG, 64, 0, stream>>>(hg, w1, b1, w2, b2, w3, b3, (float*)d_out);
}

// Round 6
// 583.068 us; speedup vs baseline: 10.6164x; 1.0114x over previous
//
#include <hip/hip_runtime.h>
#include <hip/hip_bf16.h>
#include <float.h>
#include <math.h>

#define NN 30000
#define NE 70000
#define NG 1024
#define NT 5
#define FI 75
#define NL 4

// AVG_DEG_LOG = (100*ln2 + 400*ln3 + 300*ln4 + 50*ln5)/850
#define AMP_DENOM 1.1824939264481302f

// ABH: [NN][832] bf16 : cols 0..374 = A (h@Wdst), 375..749 = B (h@Wsrc),
//                        750..824 = hterm (h@post_w rows 0..74), 825..831 pad
#define ABW 832
// AGG: [NN][1600] bf16 : per tower t (5): 320 = 4 stats x 76 (75 + pad) + 16 k-pad, pads zero
#define AGW 1600
// hb: [NN][96] bf16, cols 75..95 zero.  WcatT: [NL][832][96] bf16, k rows 75..95 zero.
#define HBW 96
// Wpost2: [NL][NT][3 s][16 col][SBH k] bf16 (k<304 real = stat*76+of, rest zero; col 15 zero)
#define SBH 328

typedef __attribute__((ext_vector_type(8))) short bf16x8;
typedef __attribute__((ext_vector_type(4))) float f32x4;

__device__ __forceinline__ float bf2f(unsigned short u) {
    return __uint_as_float(((unsigned int)u) << 16);
}
__device__ __forceinline__ unsigned short f2bf(float f) {
    __hip_bfloat16 h = __float2bfloat16(f);
    return *reinterpret_cast<unsigned short*>(&h);
}

// ---------------- CSR build ----------------
__global__ __launch_bounds__(256) void k_deg(const int* __restrict__ dst, int* __restrict__ deg) {
    int e = blockIdx.x * 256 + threadIdx.x;
    if (e < NE) atomicAdd(&deg[dst[e]], 1);
}

__global__ __launch_bounds__(1024) void k_scan(const int* __restrict__ deg, int* __restrict__ rowptr) {
    __shared__ int wsum[16];
    __shared__ int s_carry;
    int tid = threadIdx.x;
    int lane = tid & 63, wv = tid >> 6;
    if (tid == 0) s_carry = 0;
    __syncthreads();
    for (int base = 0; base < NN; base += 1024) {
        int i = base + tid;
        int v = (i < NN) ? deg[i] : 0;
        int x = v;
        #pragma unroll
        for (int off = 1; off < 64; off <<= 1) {
            int t = __shfl_up(x, off);
            if (lane >= off) x += t;
        }
        if (lane == 63) wsum[wv] = x;
        __syncthreads();
        if (tid < 16) {
            int y = wsum[tid];
            #pragma unroll
            for (int off = 1; off < 16; off <<= 1) {
                int t = __shfl_up(y, off);
                if (tid >= off) y += t;
            }
            wsum[tid] = y;
        }
        __syncthreads();
        int wbase = ((wv > 0) ? wsum[wv - 1] : 0) + s_carry;
        if (i < NN) rowptr[i] = wbase + x - v;
        int tot = wsum[15];
        __syncthreads();
        if (tid == 0) s_carry += tot;
    }
    __syncthreads();
    if (tid == 0) rowptr[NN] = s_carry;
}

__global__ __launch_bounds__(256) void k_scatter(const int* __restrict__ src, const int* __restrict__ dst,
                                                 const int* __restrict__ attr, const int* __restrict__ rowptr,
                                                 int* __restrict__ fill, int* __restrict__ csr) {
    int e = blockIdx.x * 256 + threadIdx.x;
    if (e < NE) {
        int d = dst[e];
        int pos = rowptr[d] + atomicAdd(&fill[d], 1);
        csr[pos] = src[e] | (attr[e] << 20);
    }
}

// amp/inv per node (degree-only, layer-invariant)
__global__ __launch_bounds__(256) void k_amp(const int* __restrict__ rowptr,
                                             float* __restrict__ amp, float* __restrict__ inv) {
    int n = blockIdx.x * 256 + threadIdx.x;
    if (n < NN) {
        int dg = rowptr[n + 1] - rowptr[n];
        float cnt = fmaxf((float)dg, 1.0f);
        float a = logf(cnt + 1.0f) * (1.0f / AMP_DENOM);
        amp[n] = a;
        inv[n] = 1.0f / a;
    }
}

// ---------------- embedding: hb bf16 (with zero k-pad) ----------------
__global__ __launch_bounds__(256) void k_h0(const int* __restrict__ x, const float* __restrict__ emb,
                                            unsigned short* __restrict__ hb) {
    int idx = blockIdx.x * 256 + threadIdx.x;
    if (idx < NN * HBW) {
        int n = idx / HBW, f = idx % HBW;
        hb[idx] = (f < FI) ? f2bf(emb[x[n] * FI + f]) : (unsigned short)0;
    }
}

// ---------------- Wpost2 pack (all layers, once): [NL][NT][3][16][SBH] bf16 ----------------
__global__ __launch_bounds__(256) void k_wprep3(const float* __restrict__ post_w,
                                                unsigned short* __restrict__ Wpost2) {
    int idx = blockIdx.x * 256 + threadIdx.x;
    if (idx >= NL * NT * 3 * 16 * SBH) return;
    int kk = idx % SBH;
    int col = (idx / SBH) & 15;
    int s = (idx / (SBH * 16)) % 3;
    int t = (idx / (SBH * 16 * 3)) % NT;
    int l = idx / (SBH * 16 * 3 * NT);
    float val = 0.0f;
    if (kk < 304 && col < 15) {
        int stat = kk / 76, of = kk - stat * 76;
        if (of < 75)
            val = post_w[((size_t)(l * NT + t) * 975 + 75 + s * 300 + stat * 75 + of) * 15 + col];
    }
    Wpost2[idx] = f2bf(val);
}

// ---------------- WcatT pack for MFMA preab: [NL][832 j][96 k] bf16 ----------------
__global__ __launch_bounds__(256) void k_wprep2(const float* __restrict__ pre_w,
                                                const float* __restrict__ post_w,
                                                unsigned short* __restrict__ WcatT) {
    int idx = blockIdx.x * 256 + threadIdx.x;
    if (idx >= NL * 832 * 96) return;
    int k = idx % 96;
    int j = (idx / 96) % 832;
    int l = idx / (96 * 832);
    float val = 0.0f;
    if (k < 75) {
        if (j < 375) {
            int t = j / 75, o = j % 75;
            val = pre_w[((size_t)(l * NT + t) * 225 + k) * FI + o];
        } else if (j < 750) {
            int jm = j - 375;
            int t = jm / 75, o = jm % 75;
            val = pre_w[((size_t)(l * NT + t) * 225 + 75 + k) * FI + o];
        } else if (j < 825) {
            int c = j - 750;
            int t = c / 15, o = c % 15;
            val = post_w[((size_t)(l * NT + t) * 975 + k) * 15 + o];
        }
    }
    WcatT[idx] = f2bf(val);
}

// ---------------- linT pack: [NL][80 c][96 k] bf16 (lin_w transposed, zero-padded) ----------------
__global__ __launch_bounds__(256) void k_wprep4(const float* __restrict__ lin_w,
                                                unsigned short* __restrict__ linT) {
    int idx = blockIdx.x * 256 + threadIdx.x;
    if (idx >= NL * 80 * 96) return;
    int k = idx % 96;
    int c = (idx / 96) % 80;
    int l = idx / (96 * 80);
    float v = 0.0f;
    if (k < 75 && c < 75) v = lin_w[(size_t)l * 5625 + k * 75 + c];
    linT[idx] = f2bf(v);
}

// ---------------- edge-type tables for ALL layers (4 blocks) ----------------
__global__ __launch_bounds__(384) void k_tbl4(const float* __restrict__ edge_emb, const float* __restrict__ enc_w,
                                              const float* __restrict__ enc_b, const float* __restrict__ pre_w,
                                              const float* __restrict__ pre_b, float* __restrict__ tbl4) {
    __shared__ float e4[4][FI];
    int l = blockIdx.x;
    int tid = threadIdx.x;
    float* tbl = tbl4 + l * 1500;
    if (tid < 300) {
        int a = tid / FI, f = tid % FI;
        float acc = enc_b[l * FI + f];
        for (int k = 0; k < 50; k++)
            acc += edge_emb[a * 50 + k] * enc_w[(l * 50 + k) * FI + f];
        e4[a][f] = acc;
    }
    __syncthreads();
    for (int idx = tid; idx < 4 * 375; idx += 384) {
        int a = idx / 375, c = idx % 375;
        int t = c / FI, o = c % FI;
        const float* wp = pre_w + ((size_t)(l * NT + t) * 225 + 150) * FI + o;
        float acc = pre_b[(l * NT + t) * FI + o];
        for (int f = 0; f < FI; f++)
            acc += e4[a][f] * wp[f * FI];
        tbl[idx] = acc;
    }
}

// ---------------- MFMA ABH = bn_relu(z) @ WcatT^T, BN fused (l>0) ----------------
__global__ __launch_bounds__(256) void k_preab(const unsigned short* __restrict__ hb,
                                               const float* __restrict__ zz,
                                               const float* __restrict__ bnsumP,
                                               const float* __restrict__ bngP,
                                               const float* __restrict__ bnbP,
                                               const unsigned short* __restrict__ WcatT,
                                               int l, __hip_bfloat16* __restrict__ ABH) {
    __shared__ __align__(16) unsigned short sA[128 * 104];
    __shared__ __align__(16) unsigned short sB[208 * 104];
    __shared__ float s_sc[75], s_sh[75];
    int tid = threadIdx.x;
    int m0 = blockIdx.x * 128;
    int j0 = blockIdx.y * 208;

    if (l > 0 && tid < 75) {
        float mu = bnsumP[tid] * (1.0f / NN);
        float msq = bnsumP[76 + tid] * (1.0f / NN);
        float var = msq - mu * mu;
        float sc = rsqrtf(var + 1e-5f) * bngP[tid];
        s_sc[tid] = sc;
        s_sh[tid] = bnbP[tid] - mu * sc;
    }
    const uint4* wsrc = (const uint4*)(WcatT + (size_t)l * 832 * 96);
    for (int c = tid; c < 208 * 12; c += 256) {
        int r = c / 12, q = c % 12;
        *(uint4*)&sB[r * 104 + q * 8] = wsrc[(size_t)(j0 + r) * 12 + q];
    }
    if (l == 0) {
        const uint4* hsrc = (const uint4*)hb;
        for (int c = tid; c < 128 * 12; c += 256) {
            int r = c / 12, q = c % 12;
            int n = m0 + r;
            uint4 v = make_uint4(0, 0, 0, 0);
            if (n < NN) v = hsrc[(size_t)n * 12 + q];
            *(uint4*)&sA[r * 104 + q * 8] = v;
        }
    } else {
        __syncthreads();   // s_sc/s_sh ready
        for (int idx = tid; idx < 128 * 96; idx += 256) {
            int r = idx / 96, c = idx - (idx / 96) * 96;
            int n = m0 + r;
            float v = 0.0f;
            if (c < 75 && n < NN) {
                v = zz[(size_t)n * 75 + c];
                v = fmaxf(v * s_sc[c] + s_sh[c], 0.0f);
            }
            sA[r * 104 + c] = f2bf(v);
        }
    }
    __syncthreads();

    int w = tid >> 6, lane = tid & 63;
    int mw = w * 32;
    int lr = lane & 15, lq = lane >> 4;

    bf16x8 af[2][3];
    #pragma unroll
    for (int mt = 0; mt < 2; mt++)
        #pragma unroll
        for (int ks = 0; ks < 3; ks++)
            af[mt][ks] = *(const bf16x8*)&sA[(mw + mt * 16 + lr) * 104 + ks * 32 + lq * 8];

    f32x4 acc[13][2];
    #pragma unroll
    for (int nt = 0; nt < 13; nt++)
        #pragma unroll
        for (int mt = 0; mt < 2; mt++)
            acc[nt][mt] = (f32x4){0.0f, 0.0f, 0.0f, 0.0f};

    #pragma unroll
    for (int nt = 0; nt < 13; nt++) {
        #pragma unroll
        for (int ks = 0; ks < 3; ks++) {
            bf16x8 bf = *(const bf16x8*)&sB[(nt * 16 + lr) * 104 + ks * 32 + lq * 8];
            acc[nt][0] = __builtin_amdgcn_mfma_f32_16x16x32_bf16(af[0][ks], bf, acc[nt][0], 0, 0, 0);
            acc[nt][1] = __builtin_amdgcn_mfma_f32_16x16x32_bf16(af[1][ks], bf, acc[nt][1], 0, 0, 0);
        }
    }

    // epilogue: C/D mapping col=lane&15, row=(lane>>4)*4+reg  [measured m89/m91]
    #pragma unroll
    for (int nt = 0; nt < 13; nt++) {
        int col = j0 + nt * 16 + lr;
        #pragma unroll
        for (int mt = 0; mt < 2; mt++) {
            #pragma unroll
            for (int r = 0; r < 4; r++) {
                int n = m0 + mw + mt * 16 + lq * 4 + r;
                if (n < NN) ABH[(size_t)n * ABW + col] = __float2bfloat16(acc[nt][mt][r]);
            }
        }
    }
}

// ---------------- gather: per-node stats -> AGG bf16 (stride 1600, padded) ----------------
__global__ __launch_bounds__(256) void k_gather(const __hip_bfloat16* __restrict__ ABH,
                                                const float* __restrict__ tbl,
                                                const int* __restrict__ rowptr, const int* __restrict__ csr,
                                                unsigned short* __restrict__ AGG) {
    __shared__ float s_tbl[1500];
    int tid = threadIdx.x;
    for (int i = tid; i < 1500; i += 256) s_tbl[i] = tbl[i];
    __syncthreads();

    int w = tid >> 6, l = tid & 63;
    int n = blockIdx.x * 4 + w;
    int base = rowptr[n];
    int dg = rowptr[n + 1] - base;

    float sum[6], ss[6], mn[6], mx[6];
    #pragma unroll
    for (int j = 0; j < 6; j++) { sum[j] = 0.f; ss[j] = 0.f; mn[j] = FLT_MAX; mx[j] = -FLT_MAX; }

    const unsigned short* abu = (const unsigned short*)ABH;
    int k = 0;
    for (; k + 1 < dg; k += 2) {
        int pk0 = csr[base + k], pk1 = csr[base + k + 1];
        const unsigned short* bp0 = abu + (size_t)(pk0 & 0xFFFFF) * ABW + 375;
        const unsigned short* bp1 = abu + (size_t)(pk1 & 0xFFFFF) * ABW + 375;
        const float* tp0 = s_tbl + (pk0 >> 20) * 375;
        const float* tp1 = s_tbl + (pk1 >> 20) * 375;
        #pragma unroll
        for (int j = 0; j < 6; j++) {
            int f = l + 64 * j;
            if (f < 375) {
                float v0 = bf2f(bp0[f]) + tp0[f];
                float v1 = bf2f(bp1[f]) + tp1[f];
                sum[j] += v0 + v1;
                ss[j] += v0 * v0 + v1 * v1;
                mn[j] = fminf(mn[j], fminf(v0, v1));
                mx[j] = fmaxf(mx[j], fmaxf(v0, v1));
            }
        }
    }
    if (k < dg) {
        int pk0 = csr[base + k];
        const unsigned short* bp0 = abu + (size_t)(pk0 & 0xFFFFF) * ABW + 375;
        const float* tp0 = s_tbl + (pk0 >> 20) * 375;
        #pragma unroll
        for (int j = 0; j < 6; j++) {
            int f = l + 64 * j;
            if (f < 375) {
                float v0 = bf2f(bp0[f]) + tp0[f];
                sum[j] += v0; ss[j] += v0 * v0;
                mn[j] = fminf(mn[j], v0); mx[j] = fmaxf(mx[j], v0);
            }
        }
    }

    unsigned short* out = AGG + (size_t)n * AGW;
    if (dg > 0) {
        float rc = 1.0f / (float)dg;
        const unsigned short* ap = abu + (size_t)n * ABW;
        #pragma unroll
        for (int j = 0; j < 6; j++) {
            int f = l + 64 * j;
            if (f < 375) {
                int t = f / 75, of = f - t * 75;
                int o = t * 320 + of;
                float Af = bf2f(ap[f]);
                float mean = sum[j] * rc;
                float var = ss[j] * rc - mean * mean;
                out[o]       = f2bf(Af + mean);
                out[o + 76]  = f2bf(Af + mn[j]);
                out[o + 152] = f2bf(Af + mx[j]);
                out[o + 228] = f2bf(sqrtf(fmaxf(var, 0.0f) + 1e-5f));
            }
        }
    } else {
        unsigned short zz = 0;
        unsigned short sd = f2bf(0.0031622776601683794f);  // sqrt(1e-5)
        #pragma unroll
        for (int j = 0; j < 6; j++) {
            int f = l + 64 * j;
            if (f < 375) {
                int t = f / 75, of = f - t * 75;
                int o = t * 320 + of;
                out[o] = zz; out[o + 76] = zz; out[o + 152] = zz; out[o + 228] = sd;
            }
        }
    }
    // zero pads: per tower k in [304,320), and stat pads of==75 (k = stat*76+75)
    for (int i = l; i < 80; i += 64) out[(i >> 4) * 320 + 304 + (i & 15)] = 0;
    if (l < 20) out[(l >> 2) * 320 + (l & 3) * 76 + 75] = 0;
}

// ---------------- post: MFMA tower-GEMMs + combine + MFMA lin + BN partials ----------------
__global__ __launch_bounds__(256) void k_post(const __hip_bfloat16* __restrict__ ABH,
                                              const unsigned short* __restrict__ AGG,
                                              const unsigned short* __restrict__ Wpost2,
                                              const unsigned short* __restrict__ linT,
                                              const float* __restrict__ amp_a, const float* __restrict__ inv_a,
                                              const float* __restrict__ post_b, const float* __restrict__ lin_b,
                                              int l, float* __restrict__ z, float* __restrict__ bnsum) {
    __shared__ __align__(16) unsigned short s_y[128 * 96];   // 24576 B, bf16, cols 75..95 zero
    __shared__ float s_bn[152];

    int tid = threadIdx.x;
    int n0 = blockIdx.x * 128;
    int w = tid >> 6, lane = tid & 63;
    int lr = lane & 15, lq = lane >> 4;
    int mw = w * 32;
    if (tid < 152) s_bn[tid] = 0.0f;
    for (int i = tid; i < 128 * 21; i += 256) {
        int r = i / 21, c = 75 + (i - (i / 21) * 21);
        s_y[r * 96 + c] = 0;
    }

    float am[2][4], iv[2][4];
    int rown[2][4];
    #pragma unroll
    for (int mt = 0; mt < 2; mt++)
        #pragma unroll
        for (int r = 0; r < 4; r++) {
            int n = n0 + mw + mt * 16 + lq * 4 + r;
            int nc = (n < NN) ? n : (NN - 1);
            rown[mt][r] = nc;
            am[mt][r] = amp_a[nc];
            iv[mt][r] = inv_a[nc];
        }
    int arow[2];
    #pragma unroll
    for (int mt = 0; mt < 2; mt++) {
        int n = n0 + mw + mt * 16 + lr;
        arow[mt] = (n < NN) ? n : (NN - 1);
    }

    const unsigned short* abu = (const unsigned short*)ABH;

    for (int t = 0; t < NT; t++) {
        // B read direct from global (L1/L2-hot; shared by all blocks)
        const unsigned short* wt = Wpost2 + ((size_t)((l * NT + t) * 3 * 16) + lr) * SBH;
        const unsigned short* a0p = AGG + (size_t)arow[0] * AGW + t * 320;
        const unsigned short* a1p = AGG + (size_t)arow[1] * AGW + t * 320;

        f32x4 acc[2][3];
        #pragma unroll
        for (int mt = 0; mt < 2; mt++)
            #pragma unroll
            for (int s = 0; s < 3; s++)
                acc[mt][s] = (f32x4){0.0f, 0.0f, 0.0f, 0.0f};

        #pragma unroll
        for (int ks = 0; ks < 10; ks++) {
            int off = ks * 32 + lq * 8;
            bf16x8 b0 = *(const bf16x8*)&wt[off];
            bf16x8 b1 = *(const bf16x8*)&wt[16 * SBH + off];
            bf16x8 b2 = *(const bf16x8*)&wt[32 * SBH + off];
            bf16x8 a0 = *(const bf16x8*)&a0p[off];
            bf16x8 a1 = *(const bf16x8*)&a1p[off];
            acc[0][0] = __builtin_amdgcn_mfma_f32_16x16x32_bf16(a0, b0, acc[0][0], 0, 0, 0);
            acc[0][1] = __builtin_amdgcn_mfma_f32_16x16x32_bf16(a0, b1, acc[0][1], 0, 0, 0);
            acc[0][2] = __builtin_amdgcn_mfma_f32_16x16x32_bf16(a0, b2, acc[0][2], 0, 0, 0);
            acc[1][0] = __builtin_amdgcn_mfma_f32_16x16x32_bf16(a1, b0, acc[1][0], 0, 0, 0);
            acc[1][1] = __builtin_amdgcn_mfma_f32_16x16x32_bf16(a1, b1, acc[1][1], 0, 0, 0);
            acc[1][2] = __builtin_amdgcn_mfma_f32_16x16x32_bf16(a1, b2, acc[1][2], 0, 0, 0);
        }

        if (lr < 15) {
            float qb = post_b[(l * NT + t) * 15 + lr];
            #pragma unroll
            for (int mt = 0; mt < 2; mt++)
                #pragma unroll
                for (int r = 0; r < 4; r++) {
                    float ht = bf2f(abu[(size_t)rown[mt][r] * ABW + 750 + t * 15 + lr]);
                    float y = acc[mt][0][r] + am[mt][r] * acc[mt][1][r] + iv[mt][r] * acc[mt][2][r] + ht + qb;
                    s_y[(mw + mt * 16 + lq * 4 + r) * 96 + t * 15 + lr] = f2bf(y);
                }
        }
    }
    __syncthreads();

    // lin via MFMA: z_tile = y[128,96] @ linT[80,96]^T  (wave reads only its own 32 rows)
    const unsigned short* lt = linT + (size_t)l * 80 * 96;
    bf16x8 af[2][3];
    #pragma unroll
    for (int mt = 0; mt < 2; mt++)
        #pragma unroll
        for (int ks = 0; ks < 3; ks++)
            af[mt][ks] = *(const bf16x8*)&s_y[(mw + mt * 16 + lr) * 96 + ks * 32 + lq * 8];

    f32x4 acc2[5][2];
    #pragma unroll
    for (int nt = 0; nt < 5; nt++)
        #pragma unroll
        for (int mt = 0; mt < 2; mt++)
            acc2[nt][mt] = (f32x4){0.0f, 0.0f, 0.0f, 0.0f};

    #pragma unroll
    for (int nt = 0; nt < 5; nt++) {
        #pragma unroll
        for (int ks = 0; ks < 3; ks++) {
            bf16x8 bf = *(const bf16x8*)&lt[(nt * 16 + lr) * 96 + ks * 32 + lq * 8];
            acc2[nt][0] = __builtin_amdgcn_mfma_f32_16x16x32_bf16(af[0][ks], bf, acc2[nt][0], 0, 0, 0);
            acc2[nt][1] = __builtin_amdgcn_mfma_f32_16x16x32_bf16(af[1][ks], bf, acc2[nt][1], 0, 0, 0);
        }
    }

    float b1a[5] = {}, b2a[5] = {};
    #pragma unroll
    for (int nt = 0; nt < 5; nt++) {
        int c = nt * 16 + lr;
        bool cv = (c < 75);
        float lb = cv ? lin_b[l * 75 + c] : 0.0f;
        #pragma unroll
        for (int mt = 0; mt < 2; mt++)
            #pragma unroll
            for (int r = 0; r < 4; r++) {
                int n = n0 + mw + mt * 16 + lq * 4 + r;
                if (cv && n < NN) {
                    float v = acc2[nt][mt][r] + lb;
                    z[(size_t)n * 75 + c] = v;
                    b1a[nt] += v;
                    b2a[nt] += v * v;
                }
            }
    }
    #pragma unroll
    for (int nt = 0; nt < 5; nt++) {
        b1a[nt] += __shfl_xor(b1a[nt], 16); b1a[nt] += __shfl_xor(b1a[nt], 32);
        b2a[nt] += __shfl_xor(b2a[nt], 16); b2a[nt] += __shfl_xor(b2a[nt], 32);
    }
    if (lq == 0) {
        #pragma unroll
        for (int nt = 0; nt < 5; nt++) {
            int c = nt * 16 + lr;
            if (c < 75) {
                atomicAdd(&s_bn[c], b1a[nt]);
                atomicAdd(&s_bn[76 + c], b2a[nt]);
            }
        }
    }
    __syncthreads();
    if (tid < 75) {
        atomicAdd(&bnsum[tid], s_bn[tid]);
        atomicAdd(&bnsum[76 + tid], s_bn[76 + tid]);
    }
}

// ---------------- pooling (BN fused) + MLP ----------------
__global__ __launch_bounds__(256) void k_pool(const float* __restrict__ z, const float* __restrict__ bnsum3,
                                              const float* __restrict__ bng, const float* __restrict__ bnb,
                                              const int* __restrict__ batch, float* __restrict__ hg) {
    __shared__ float s_sc[75], s_sh[75];
    int tid = threadIdx.x;
    if (tid < 75) {
        float mu = bnsum3[tid] * (1.0f / NN);
        float msq = bnsum3[76 + tid] * (1.0f / NN);
        float var = msq - mu * mu;
        float sc = rsqrtf(var + 1e-5f) * bng[tid];
        s_sc[tid] = sc;
        s_sh[tid] = bnb[tid] - mu * sc;
    }
    __syncthreads();
    int idx = blockIdx.x * 256 + tid;
    if (idx < NN * 75) {
        int n = idx / 75, f = idx % 75;
        float v = fmaxf(z[idx] * s_sc[f] + s_sh[f], 0.0f);
        atomicAdd(&hg[batch[n] * 75 + f], v);
    }
}

__global__ __launch_bounds__(64) void k_mlp(const float* __restrict__ hg,
                                            const float* __restrict__ w1, const float* __restrict__ b1,
                                            const float* __restrict__ w2, const float* __restrict__ b2,
                                            const float* __restrict__ w3, const float* __restrict__ b3,
                                            float* __restrict__ out) {
    __shared__ float zin[75], z1[50], z2[25];
    int g = blockIdx.x, tid = threadIdx.x;
    for (int k = tid; k < 75; k += 64) zin[k] = hg[g * 75 + k];
    __syncthreads();
    if (tid < 50) {
        float acc = b1[tid];
        for (int k = 0; k < 75; k++) acc += zin[k] * w1[k * 50 + tid];
        z1[tid] = fmaxf(acc, 0.0f);
    }
    __syncthreads();
    if (tid < 25) {
        float acc = b2[tid];
        for (int k = 0; k < 50; k++) acc += z1[k] * w2[k * 25 + tid];
        z2[tid] = fmaxf(acc, 0.0f);
    }
    __syncthreads();
    if (tid == 0) {
        float acc = b3[0];
        for (int k = 0; k < 25; k++) acc += z2[k] * w3[k];
        out[g] = acc;
    }
}

extern "C" void kernel_launch(void* const* d_in, const int* in_sizes, int n_in,
                              void* d_out, int out_size, void* d_ws, size_t ws_size,
                              hipStream_t stream) {
    const int* x        = (const int*)d_in[0];
    const int* ei       = (const int*)d_in[1];
    const int* eattr    = (const int*)d_in[2];
    const int* batch    = (const int*)d_in[3];
    const float* node_emb = (const float*)d_in[4];
    const float* edge_emb = (const float*)d_in[5];
    const float* enc_w  = (const float*)d_in[6];
    const float* enc_b  = (const float*)d_in[7];
    const float* pre_w  = (const float*)d_in[8];
    const float* pre_b  = (const float*)d_in[9];
    const float* post_w = (const float*)d_in[10];
    const float* post_b = (const float*)d_in[11];
    const float* lin_w  = (const float*)d_in[12];
    const float* lin_b  = (const float*)d_in[13];
    const float* bn_g   = (const float*)d_in[14];
    const float* bn_b   = (const float*)d_in[15];
    const float* w1     = (const float*)d_in[16];
    const float* b1     = (const float*)d_in[17];
    const float* w2     = (const float*)d_in[18];
    const float* b2     = (const float*)d_in[19];
    const float* w3     = (const float*)d_in[20];
    const float* b3     = (const float*)d_in[21];

    char* p = (char*)d_ws;
    auto carve = [&](size_t bytes) -> char* {
        char* r = p;
        p += ((bytes + 255) & ~(size_t)255);
        return r;
    };
    __hip_bfloat16* ABH = (__hip_bfloat16*)carve((size_t)NN * ABW * 2);
    unsigned short* AGG = (unsigned short*)carve((size_t)NN * AGW * 2);
    float* z     = (float*)carve((size_t)NN * 75 * 4);
    unsigned short* hb = (unsigned short*)carve((size_t)NN * HBW * 2);
    unsigned short* WcatT = (unsigned short*)carve((size_t)NL * 832 * 96 * 2);
    unsigned short* Wpost2 = (unsigned short*)carve((size_t)NL * NT * 3 * 16 * SBH * 2);
    unsigned short* linT = (unsigned short*)carve((size_t)NL * 80 * 96 * 2);
    float* tbl4  = (float*)carve((size_t)NL * 1500 * 4);
    int* deg     = (int*)carve(NN * 4);
    int* rowptr  = (int*)carve((NN + 1) * 4);
    int* fill    = (int*)carve(NN * 4);
    int* csr     = (int*)carve(NE * 4);
    float* bnsum = (float*)carve((size_t)NL * 152 * 4);
    float* amp_a = (float*)carve(NN * 4);
    float* inv_a = (float*)carve(NN * 4);
    float* hg    = (float*)carve((size_t)NG * 75 * 4);

    hipMemsetAsync(deg, 0, NN * 4, stream);
    hipMemsetAsync(fill, 0, NN * 4, stream);
    hipMemsetAsync(hg, 0, (size_t)NG * 75 * 4, stream);
    hipMemsetAsync(bnsum, 0, (size_t)NL * 152 * 4, stream);

    k_deg<<<(NE + 255) / 256, 256, 0, stream>>>(ei + NE, deg);
    k_scan<<<1, 1024, 0, stream>>>(deg, rowptr);
    k_scatter<<<(NE + 255) / 256, 256, 0, stream>>>(ei, ei + NE, eattr, rowptr, fill, csr);
    k_amp<<<(NN + 255) / 256, 256, 0, stream>>>(rowptr, amp_a, inv_a);
    k_h0<<<(NN * HBW + 255) / 256, 256, 0, stream>>>(x, node_emb, hb);
    k_wprep3<<<(NL * NT * 3 * 16 * SBH + 255) / 256, 256, 0, stream>>>(post_w, Wpost2);
    k_wprep2<<<(NL * 832 * 96 + 255) / 256, 256, 0, stream>>>(pre_w, post_w, WcatT);
    k_wprep4<<<(NL * 80 * 96 + 255) / 256, 256, 0, stream>>>(lin_w, linT);
    k_tbl4<<<NL, 384, 0, stream>>>(edge_emb, enc_w, enc_b, pre_w, pre_b, tbl4);

    for (int l = 0; l < NL; l++) {
        k_preab<<<dim3((NN + 127) / 128, 4), 256, 0, stream>>>(
            hb, z, bnsum + (l > 0 ? (l - 1) * 152 : 0),
            bn_g + (l > 0 ? (l - 1) * 75 : 0), bn_b + (l > 0 ? (l - 1) * 75 : 0),
            WcatT, l, ABH);
        k_gather<<<NN / 4, 256, 0, stream>>>(ABH, tbl4 + l * 1500, rowptr, csr, AGG);
        k_post<<<(NN + 127) / 128, 256, 0, stream>>>(ABH, AGG, Wpost2, linT, amp_a, inv_a,
                                                     post_b, lin_b, l, z, bnsum + l * 152);
    }

    k_pool<<<(NN * 75 + 255) / 256, 256, 0, stream>>>(z, bnsum + 3 * 152, bn_g + 3 * 75, bn_b + 3 * 75,
                                                      batch, hg);
    k_mlp<<<NG, 64, 0, stream>>>(hg, w1, b1, w2, b2, w3, b3, (float*)d_out);
}